// Round 1
// baseline (950.961 us; speedup 1.0000x reference)
//
#include <hip/hip_runtime.h>
#include <math.h>

// Problem constants (fixed by setup_inputs)
#define BB   2
#define HH   48
#define WW   48
#define DD   512
#define DPH  64
#define NHH  8
#define NSEQ (HH*WW)      // 2304
#define HALFD 32

// ---------------------------------------------------------------------------
// Kernel 1: QKV projection + RoPE.
// grid = B*NSEQ/P1 blocks, 256 threads. Each block handles P1 positions.
// Weight layout is w[d, v, h] flat = d*512 + v*8 + h. Thread t owns flat
// columns c0 = t, c1 = t+256 so weight loads are lane-coalesced.
// ---------------------------------------------------------------------------
#define P1 8
__global__ __launch_bounds__(256) void k_qkv_rope(
    const float* __restrict__ x, const float* __restrict__ wq,
    const float* __restrict__ wk, const float* __restrict__ wv,
    const float* __restrict__ ang,
    float* __restrict__ qo, float* __restrict__ ko, float* __restrict__ vo)
{
    __shared__ float xs[P1][DD];      // 16 KB
    __shared__ float qs[P1][576];     // rope staging, layout v*9+h (pad vs bank conflicts)
    __shared__ float ks[P1][576];
    const int tid = threadIdx.x;
    const int pos0 = blockIdx.x * P1;

    // stage x rows (coalesced float4)
    const float4* xg = reinterpret_cast<const float4*>(x) + (size_t)pos0 * (DD/4);
    float4* xsv = reinterpret_cast<float4*>(&xs[0][0]);
#pragma unroll
    for (int u = 0; u < (P1*DD/4)/256; ++u)
        xsv[tid + u*256] = xg[tid + u*256];
    __syncthreads();

    float aq0[P1], aq1[P1], ak0[P1], ak1[P1], av0[P1], av1[P1];
#pragma unroll
    for (int p = 0; p < P1; ++p) { aq0[p]=0;aq1[p]=0;ak0[p]=0;ak1[p]=0;av0[p]=0;av1[p]=0; }

    for (int d = 0; d < DD; ++d) {
        float wq0 = wq[d*512 + tid], wq1 = wq[d*512 + 256 + tid];
        float wk0 = wk[d*512 + tid], wk1 = wk[d*512 + 256 + tid];
        float wv0 = wv[d*512 + tid], wv1 = wv[d*512 + 256 + tid];
#pragma unroll
        for (int p = 0; p < P1; ++p) {
            float xv = xs[p][d];
            aq0[p] = fmaf(xv, wq0, aq0[p]); aq1[p] = fmaf(xv, wq1, aq1[p]);
            ak0[p] = fmaf(xv, wk0, ak0[p]); ak1[p] = fmaf(xv, wk1, ak1[p]);
            av0[p] = fmaf(xv, wv0, av0[p]); av1[p] = fmaf(xv, wv1, av1[p]);
        }
    }

    // c0 = tid -> (h = tid&7, v = tid>>3) ; c1 = tid+256 -> (same h, v+32)
    const int h0 = tid & 7, v0 = tid >> 3;
#pragma unroll
    for (int p = 0; p < P1; ++p) {
        int pos = pos0 + p;
        int b = pos / NSEQ, rem = pos - b*NSEQ;
        // v needs no RoPE: store directly
        size_t vbase = ((size_t)(b*NHH + h0)*NSEQ + rem)*DPH;
        vo[vbase + v0]      = av0[p];
        vo[vbase + v0 + 32] = av1[p];
        // q,k: LDS roundtrip to pair up interleaved (even,odd) elements
        qs[p][v0*9 + h0]      = aq0[p];
        qs[p][(v0+32)*9 + h0] = aq1[p];
        ks[p][v0*9 + h0]      = ak0[p];
        ks[p][(v0+32)*9 + h0] = ak1[p];
    }
    __syncthreads();

    // RoPE + store: thread = (head ph, pair pc)
    const int ph = tid >> 5, pc = tid & 31;
    const float a_i = ang[pc], a_j = ang[HALFD + pc];
#pragma unroll
    for (int p = 0; p < P1; ++p) {
        int pos = pos0 + p;
        int b = pos / NSEQ, rem = pos - b*NSEQ;
        int i = rem / WW, j = rem - i*WW;
        float th = (float)i*a_i + (float)j*a_j;
        float sn, cn; sincosf(th, &sn, &cn);
        float q0 = qs[p][(2*pc)*9 + ph], q1 = qs[p][(2*pc+1)*9 + ph];
        float k0 = ks[p][(2*pc)*9 + ph], k1 = ks[p][(2*pc+1)*9 + ph];
        size_t base = ((size_t)(b*NHH + ph)*NSEQ + rem)*DPH + 2*pc;
        float2 qr; qr.x = q0*cn - q1*sn; qr.y = q0*sn + q1*cn;
        float2 kr; kr.x = k0*cn - k1*sn; kr.y = k0*sn + k1*cn;
        *reinterpret_cast<float2*>(qo + base) = qr;
        *reinterpret_cast<float2*>(ko + base) = kr;
    }
}

// ---------------------------------------------------------------------------
// Kernel 2: flash attention (fp32). TQ=16 query rows/block, KV chunks of 64.
// Online softmax; per-row state lives in a 32-lane shuffle group.
// Output written IN-PLACE over the q buffer (block reads only its own rows).
// ---------------------------------------------------------------------------
#define TQ 16
#define CK 64
#define NCHUNK (NSEQ/CK)   // 36
__global__ __launch_bounds__(256) void k_attn(
    const float* __restrict__ qf, const float* __restrict__ kf,
    const float* __restrict__ vf, float* __restrict__ of)
{
    __shared__ float qsm[TQ][68];
    __shared__ float ksm[CK][68];
    __shared__ float vsm[CK][68];
    __shared__ float psm[TQ][68];
    __shared__ float fs[TQ], ls[TQ];
    const int tid = threadIdx.x;
    const int nqb = NSEQ / TQ;                 // 144
    const int bh   = blockIdx.x / nqb;
    const int qblk = blockIdx.x - bh*nqb;
    const int row0 = qblk * TQ;
    const float* qbase = qf + ((size_t)bh*NSEQ + row0)*DPH;
    const float* kbase = kf + (size_t)bh*NSEQ*DPH;
    const float* vbase = vf + (size_t)bh*NSEQ*DPH;

    {   // stage q rows, pre-scaled by 1/sqrt(64)
        int r = tid >> 4, f = tid & 15;
        float4 qv = reinterpret_cast<const float4*>(qbase + r*DPH)[f];
        qv.x *= 0.125f; qv.y *= 0.125f; qv.z *= 0.125f; qv.w *= 0.125f;
        *reinterpret_cast<float4*>(&qsm[r][f*4]) = qv;
    }

    const int rr = tid >> 5, cc = tid & 31;    // score map: rows {2rr,2rr+1}, cols {cc,cc+32}
    const int pr = tid >> 4, pvl = tid & 15;   // PV map: row pr, v-cols 4*pvl..+3
    const int cstg = tid >> 2, fstg = tid & 3; // staging map

    float m0 = -INFINITY, m1 = -INFINITY, l0 = 0.f, l1 = 0.f;
    float4 acc = make_float4(0.f, 0.f, 0.f, 0.f);

    for (int t = 0; t < NCHUNK; ++t) {
        __syncthreads();                       // prev PV done reading vsm/psm
        const float4* kg = reinterpret_cast<const float4*>(kbase + ((size_t)t*CK + cstg)*DPH);
        const float4* vg = reinterpret_cast<const float4*>(vbase + ((size_t)t*CK + cstg)*DPH);
#pragma unroll
        for (int u = 0; u < 4; ++u) {
            *reinterpret_cast<float4*>(&ksm[cstg][(fstg + 4*u)*4]) = kg[fstg + 4*u];
            *reinterpret_cast<float4*>(&vsm[cstg][(fstg + 4*u)*4]) = vg[fstg + 4*u];
        }
        __syncthreads();

        // ---- scores: 2x2 register tile, float4 over dph
        float s00=0.f,s01=0.f,s10=0.f,s11=0.f;
        const float4* q0v = reinterpret_cast<const float4*>(&qsm[2*rr][0]);
        const float4* q1v = reinterpret_cast<const float4*>(&qsm[2*rr+1][0]);
        const float4* k0v = reinterpret_cast<const float4*>(&ksm[cc][0]);
        const float4* k1v = reinterpret_cast<const float4*>(&ksm[cc+32][0]);
#pragma unroll
        for (int dd = 0; dd < 16; ++dd) {
            float4 qa = q0v[dd], qb = q1v[dd];
            float4 ka = k0v[dd], kb = k1v[dd];
            s00 += qa.x*ka.x + qa.y*ka.y + qa.z*ka.z + qa.w*ka.w;
            s01 += qa.x*kb.x + qa.y*kb.y + qa.z*kb.z + qa.w*kb.w;
            s10 += qb.x*ka.x + qb.y*ka.y + qb.z*ka.z + qb.w*ka.w;
            s11 += qb.x*kb.x + qb.y*kb.y + qb.z*kb.z + qb.w*kb.w;
        }

        // ---- online softmax (per row, 32-lane group)
        float cm0 = fmaxf(s00, s01), cm1 = fmaxf(s10, s11);
#pragma unroll
        for (int msk = 16; msk >= 1; msk >>= 1) {
            cm0 = fmaxf(cm0, __shfl_xor(cm0, msk, 32));
            cm1 = fmaxf(cm1, __shfl_xor(cm1, msk, 32));
        }
        float m0n = fmaxf(m0, cm0), m1n = fmaxf(m1, cm1);
        float f0 = __expf(m0 - m0n), f1 = __expf(m1 - m1n);
        float p00 = __expf(s00 - m0n), p01 = __expf(s01 - m0n);
        float p10 = __expf(s10 - m1n), p11 = __expf(s11 - m1n);
        psm[2*rr][cc]        = p00; psm[2*rr][cc+32]   = p01;
        psm[2*rr+1][cc]      = p10; psm[2*rr+1][cc+32] = p11;
        float sm0 = p00 + p01, sm1 = p10 + p11;
#pragma unroll
        for (int msk = 16; msk >= 1; msk >>= 1) {
            sm0 += __shfl_xor(sm0, msk, 32);
            sm1 += __shfl_xor(sm1, msk, 32);
        }
        l0 = l0*f0 + sm0;
        l1 = l1*f1 + sm1;
        m0 = m0n; m1 = m1n;
        if (cc == 0) { fs[2*rr] = f0; fs[2*rr+1] = f1; }
        __syncthreads();

        // ---- PV accumulate
        float fr = fs[pr];
        acc.x *= fr; acc.y *= fr; acc.z *= fr; acc.w *= fr;
#pragma unroll 8
        for (int c = 0; c < CK; ++c) {
            float p = psm[pr][c];
            float4 v4 = *reinterpret_cast<const float4*>(&vsm[c][pvl*4]);
            acc.x = fmaf(p, v4.x, acc.x);
            acc.y = fmaf(p, v4.y, acc.y);
            acc.z = fmaf(p, v4.z, acc.z);
            acc.w = fmaf(p, v4.w, acc.w);
        }
    }

    if (cc == 0) { ls[2*rr] = l0; ls[2*rr+1] = l1; }
    __syncthreads();
    float inv = 1.f / ls[pr];
    acc.x *= inv; acc.y *= inv; acc.z *= inv; acc.w *= inv;
    *reinterpret_cast<float4*>(of + ((size_t)bh*NSEQ + row0 + pr)*DPH + pvl*4) = acc;
}

// ---------------------------------------------------------------------------
// Kernel 3: output projection. out[b,i,j,d] = sum_{h,v} att[b,h,pos,v]*wo[d,v,h].
// P3 positions/block; wo tiles staged TRANSPOSED ([e][d]) for conflict-free reads.
// ---------------------------------------------------------------------------
#define P3 8
__global__ __launch_bounds__(256) void k_oproj(
    const float* __restrict__ att, const float* __restrict__ wo,
    float* __restrict__ out)
{
    __shared__ float asm_[P3][512];   // att, reordered e = v*8+h (matches wo row order)
    __shared__ float wsm[64][68];     // transposed tile [e][d]
    const int tid = threadIdx.x;
    const int pos0 = blockIdx.x * P3;

#pragma unroll
    for (int p = 0; p < P3; ++p) {
        int pos = pos0 + p;
        int b = pos / NSEQ, rem = pos - b*NSEQ;
#pragma unroll
        for (int u = 0; u < 2; ++u) {
            int e = tid + 256*u;
            int h = e & 7, v = e >> 3;
            asm_[p][e] = att[((size_t)(b*NHH + h)*NSEQ + rem)*DPH + v];
        }
    }

    const int pp = tid >> 5, dl = tid & 31;    // position, d-lane
    const int rstg = tid >> 2, fstg = tid & 3; // staging map
    const int pos = pos0 + pp;

    for (int dt = 0; dt < 8; ++dt) {
        float acc0 = 0.f, acc1 = 0.f;
        for (int et = 0; et < 8; ++et) {
            __syncthreads();   // prev tile consumed (also covers asm_ staging at dt=et=0)
            const float4* wg = reinterpret_cast<const float4*>(
                wo + (size_t)(dt*64 + rstg)*512 + et*64);
#pragma unroll
            for (int u = 0; u < 4; ++u) {
                float4 w4 = wg[fstg + 4*u];
                int e0 = (fstg + 4*u)*4;
                wsm[e0+0][rstg] = w4.x;
                wsm[e0+1][rstg] = w4.y;
                wsm[e0+2][rstg] = w4.z;
                wsm[e0+3][rstg] = w4.w;
            }
            __syncthreads();
#pragma unroll 16
            for (int ee = 0; ee < 64; ++ee) {
                float a = asm_[pp][et*64 + ee];
                acc0 = fmaf(a, wsm[ee][dl],      acc0);
                acc1 = fmaf(a, wsm[ee][dl+32],   acc1);
            }
        }
        out[(size_t)pos*DD + dt*64 + dl]      = acc0;
        out[(size_t)pos*DD + dt*64 + dl + 32] = acc1;
    }
}

// ---------------------------------------------------------------------------
extern "C" void kernel_launch(void* const* d_in, const int* in_sizes, int n_in,
                              void* d_out, int out_size, void* d_ws, size_t ws_size,
                              hipStream_t stream) {
    const float* x   = (const float*)d_in[0];
    const float* wq  = (const float*)d_in[1];
    const float* wk  = (const float*)d_in[2];
    const float* wv  = (const float*)d_in[3];
    const float* wo  = (const float*)d_in[4];
    const float* ang = (const float*)d_in[5];
    float* out = (float*)d_out;

    const size_t per = (size_t)BB*NHH*NSEQ*DPH;   // 2.36M floats per buffer
    float* qb = (float*)d_ws;
    float* kb = qb + per;
    float* vb = kb + per;

    k_qkv_rope<<<(BB*NSEQ)/P1, 256, 0, stream>>>(x, wq, wk, wv, ang, qb, kb, vb);
    k_attn<<<BB*NHH*(NSEQ/TQ), 256, 0, stream>>>(qb, kb, vb, qb);  // out in-place over qb
    k_oproj<<<(BB*NSEQ)/P3, 256, 0, stream>>>(qb, wo, out);
}

// Round 2
// 453.047 us; speedup vs baseline: 2.0990x; 2.0990x over previous
//
#include <hip/hip_runtime.h>
#include <math.h>

// Problem constants (fixed by setup_inputs)
#define BB   2
#define HH   48
#define WW   48
#define DD   512
#define DPH  64
#define NHH  8
#define NSEQ (HH*WW)      // 2304
#define HALFD 32

typedef __attribute__((ext_vector_type(8))) short short8v;  // 8 bf16
typedef __attribute__((ext_vector_type(4))) float f32x4;

__device__ __forceinline__ ushort f2bf(float f) {
    uint u = __float_as_uint(f);
    return (ushort)((u + 0x7fffu + ((u >> 16) & 1u)) >> 16);   // RNE
}
__device__ __forceinline__ uint pack2bf(float lo, float hi) {
    return (uint)f2bf(lo) | ((uint)f2bf(hi) << 16);
}

// ---------------------------------------------------------------------------
// Kernel 1: QKV projection + RoPE. Outputs bf16:
//   qo: [b,h,n,64] bf16, pre-scaled by 1/8 (softmax scale folded in)
//   ko: [b,h,n,64] bf16
//   vT: [b,h,64,n] bf16 (transposed so attention's PV B-operand reads are
//       contiguous); staged through LDS for 16B global stores.
// ---------------------------------------------------------------------------
#define P1 8
__global__ __launch_bounds__(256) void k_qkv_rope(
    const float* __restrict__ x, const float* __restrict__ wq,
    const float* __restrict__ wk, const float* __restrict__ wv,
    const float* __restrict__ ang,
    ushort* __restrict__ qo, ushort* __restrict__ ko, ushort* __restrict__ vT)
{
    __shared__ float xs[P1][DD];      // 16 KB; reused as v bf16 staging later
    __shared__ float qs[P1][576];     // rope staging, layout v*9+h
    __shared__ float ks[P1][576];
    const int tid = threadIdx.x;
    const int pos0 = blockIdx.x * P1;

    // stage x rows (coalesced float4)
    const float4* xg = reinterpret_cast<const float4*>(x) + (size_t)pos0 * (DD/4);
    float4* xsv = reinterpret_cast<float4*>(&xs[0][0]);
#pragma unroll
    for (int u = 0; u < (P1*DD/4)/256; ++u)
        xsv[tid + u*256] = xg[tid + u*256];
    __syncthreads();

    float aq0[P1], aq1[P1], ak0[P1], ak1[P1], av0[P1], av1[P1];
#pragma unroll
    for (int p = 0; p < P1; ++p) { aq0[p]=0;aq1[p]=0;ak0[p]=0;ak1[p]=0;av0[p]=0;av1[p]=0; }

    for (int d = 0; d < DD; ++d) {
        float wq0 = wq[d*512 + tid], wq1 = wq[d*512 + 256 + tid];
        float wk0 = wk[d*512 + tid], wk1 = wk[d*512 + 256 + tid];
        float wv0 = wv[d*512 + tid], wv1 = wv[d*512 + 256 + tid];
#pragma unroll
        for (int p = 0; p < P1; ++p) {
            float xv = xs[p][d];
            aq0[p] = fmaf(xv, wq0, aq0[p]); aq1[p] = fmaf(xv, wq1, aq1[p]);
            ak0[p] = fmaf(xv, wk0, ak0[p]); ak1[p] = fmaf(xv, wk1, ak1[p]);
            av0[p] = fmaf(xv, wv0, av0[p]); av1[p] = fmaf(xv, wv1, av1[p]);
        }
    }

    // c0 = tid -> (h = tid&7, v = tid>>3) ; c1 = tid+256 -> (same h, v+32)
    const int h0 = tid & 7, v0 = tid >> 3;
#pragma unroll
    for (int p = 0; p < P1; ++p) {
        qs[p][v0*9 + h0]      = aq0[p];
        qs[p][(v0+32)*9 + h0] = aq1[p];
        ks[p][v0*9 + h0]      = ak0[p];
        ks[p][(v0+32)*9 + h0] = ak1[p];
    }
    __syncthreads();   // qs/ks staged; xs fully consumed -> safe to alias

    // v: stage bf16 into (aliased) LDS in transposed-run layout [e=h*64+d][p]
    ushort* vst = reinterpret_cast<ushort*>(&xs[0][0]);  // 512 x 8 ushorts = 8 KB
    const int e0 = h0*64 + v0, e1 = h0*64 + v0 + 32;
#pragma unroll
    for (int p = 0; p < P1; ++p) {
        vst[e0*8 + p] = f2bf(av0[p]);
        vst[e1*8 + p] = f2bf(av1[p]);
    }

    // RoPE + store q,k bf16: thread = (head ph, pair pc)
    const int ph = tid >> 5, pc = tid & 31;
    const float a_i = ang[pc], a_j = ang[HALFD + pc];
#pragma unroll
    for (int p = 0; p < P1; ++p) {
        int pos = pos0 + p;
        int b = pos / NSEQ, rem = pos - b*NSEQ;
        int i = rem / WW, j = rem - i*WW;
        float th = (float)i*a_i + (float)j*a_j;
        float sn, cn; sincosf(th, &sn, &cn);
        float q0 = qs[p][(2*pc)*9 + ph], q1 = qs[p][(2*pc+1)*9 + ph];
        float k0 = ks[p][(2*pc)*9 + ph], k1 = ks[p][(2*pc+1)*9 + ph];
        float qrx = (q0*cn - q1*sn)*0.125f, qry = (q0*sn + q1*cn)*0.125f;
        float krx =  k0*cn - k1*sn,        kry =  k0*sn + k1*cn;
        size_t ubase = ((size_t)(b*NHH + ph)*NSEQ + rem)*32 + pc;  // uint index
        reinterpret_cast<uint*>(qo)[ubase] = pack2bf(qrx, qry);
        reinterpret_cast<uint*>(ko)[ubase] = pack2bf(krx, kry);
    }
    __syncthreads();   // vst staged

    // v transposed stores: thread t writes 16B runs for e = t, t+256
    const int b = pos0 / NSEQ, rem0 = pos0 - b*NSEQ;   // block never spans b
#pragma unroll
    for (int u = 0; u < 2; ++u) {
        int e = tid + 256*u;
        uint4 run = *reinterpret_cast<const uint4*>(vst + e*8);
        *reinterpret_cast<uint4*>(vT + ((size_t)(b*512 + e))*NSEQ + rem0) = run;
    }
}

// ---------------------------------------------------------------------------
// Kernel 2: flash attention, bf16 MFMA (16x16x32).
// 4 waves/block; wave w owns q rows [row0+16w, +16). KV chunks of 64 staged
// in LDS bf16 (pitch 72 vs bank conflicts). Softmax online in D-layout regs;
// P converted to A-layout via a per-wave LDS tile.
// ---------------------------------------------------------------------------
#define CK 64
#define NCHUNK (NSEQ/CK)   // 36
#define KP 72              // LDS pitch (bf16 elems)
__global__ __launch_bounds__(256) void k_attn_mfma(
    const ushort* __restrict__ qb, const ushort* __restrict__ kb,
    const ushort* __restrict__ vb, float* __restrict__ Of)
{
    __shared__ ushort ksm[CK][KP];       // K chunk, row-major [kv][d]
    __shared__ ushort vsm[CK][KP];       // V chunk, transposed [d][kv]
    __shared__ ushort psm[4][16][KP];    // per-wave P tile [q][kv]
    const int tid = threadIdx.x;
    const int w = tid >> 6, l = tid & 63;
    const int g = l >> 4, lr = l & 15;
    const int bh   = blockIdx.x / (NSEQ/64);
    const int qc   = blockIdx.x - bh*(NSEQ/64);
    const int row0 = qc * 64;
    const ushort* kbase = kb + (size_t)bh*NSEQ*DPH;
    const ushort* vbase = vb + (size_t)bh*DPH*NSEQ;

    // Q fragments (held in registers for the whole kernel)
    const ushort* qptr = qb + ((size_t)bh*NSEQ + row0 + 16*w + lr)*DPH + g*8;
    const short8v qA0 = *reinterpret_cast<const short8v*>(qptr);
    const short8v qA1 = *reinterpret_cast<const short8v*>(qptr + 32);

    float mrow[4], lrow[4];
    f32x4 o[4];
#pragma unroll
    for (int r = 0; r < 4; ++r) { mrow[r] = -INFINITY; lrow[r] = 0.f; }
#pragma unroll
    for (int vt = 0; vt < 4; ++vt) o[vt] = (f32x4){0.f,0.f,0.f,0.f};

    for (int t = 0; t < NCHUNK; ++t) {
        __syncthreads();   // all waves done reading prev chunk's ksm/vsm
#pragma unroll
        for (int i = 0; i < 2; ++i) {
            int tau = tid + 256*i;
            int row = tau >> 3, cg = tau & 7;
            *reinterpret_cast<uint4*>(&ksm[row][cg*8]) =
                *reinterpret_cast<const uint4*>(kbase + ((size_t)(t*CK + row))*DPH + cg*8);
            *reinterpret_cast<uint4*>(&vsm[row][cg*8]) =
                *reinterpret_cast<const uint4*>(vbase + (size_t)row*NSEQ + t*CK + cg*8);
        }
        __syncthreads();

        // ---- S = Q K^T : 4 tiles of 16x16, 2 mfma each
        f32x4 s[4];
#pragma unroll
        for (int tile = 0; tile < 4; ++tile) {
            short8v k0 = *reinterpret_cast<const short8v*>(&ksm[tile*16 + lr][g*8]);
            short8v k1 = *reinterpret_cast<const short8v*>(&ksm[tile*16 + lr][32 + g*8]);
            f32x4 acc = (f32x4){0.f,0.f,0.f,0.f};
            acc = __builtin_amdgcn_mfma_f32_16x16x32_bf16(qA0, k0, acc, 0, 0, 0);
            acc = __builtin_amdgcn_mfma_f32_16x16x32_bf16(qA1, k1, acc, 0, 0, 0);
            s[tile] = acc;
        }

        // ---- online softmax; lane holds rows 4g+r, cols lr+16*tile
        float f_r[4];
#pragma unroll
        for (int r = 0; r < 4; ++r) {
            float cm = fmaxf(fmaxf(s[0][r], s[1][r]), fmaxf(s[2][r], s[3][r]));
#pragma unroll
            for (int msk = 8; msk >= 1; msk >>= 1)
                cm = fmaxf(cm, __shfl_xor(cm, msk));
            float mn = fmaxf(mrow[r], cm);
            f_r[r] = __expf(mrow[r] - mn);
            mrow[r] = mn;
            float rs = 0.f;
#pragma unroll
            for (int tile = 0; tile < 4; ++tile) {
                float p = __expf(s[tile][r] - mn);
                s[tile][r] = p;
                rs += p;
            }
#pragma unroll
            for (int msk = 8; msk >= 1; msk >>= 1)
                rs += __shfl_xor(rs, msk);
            lrow[r] = lrow[r]*f_r[r] + rs;
        }

        // ---- P (D-layout) -> LDS bf16 (A-layout source)
#pragma unroll
        for (int tile = 0; tile < 4; ++tile)
#pragma unroll
            for (int r = 0; r < 4; ++r)
                psm[w][4*g + r][lr + 16*tile] = f2bf(s[tile][r]);

        // ---- rescale O by f
#pragma unroll
        for (int vt = 0; vt < 4; ++vt)
#pragma unroll
            for (int r = 0; r < 4; ++r)
                o[vt][r] *= f_r[r];

        // ---- O += P V
#pragma unroll
        for (int half = 0; half < 2; ++half) {
            short8v pA = *reinterpret_cast<const short8v*>(&psm[w][lr][32*half + g*8]);
#pragma unroll
            for (int vt = 0; vt < 4; ++vt) {
                short8v vf = *reinterpret_cast<const short8v*>(&vsm[vt*16 + lr][32*half + g*8]);
                o[vt] = __builtin_amdgcn_mfma_f32_16x16x32_bf16(pA, vf, o[vt], 0, 0, 0);
            }
        }
    }

    // ---- normalize + store fp32 O [b,h,n,64]
    float inv[4];
#pragma unroll
    for (int r = 0; r < 4; ++r) inv[r] = 1.f / lrow[r];
#pragma unroll
    for (int vt = 0; vt < 4; ++vt)
#pragma unroll
        for (int r = 0; r < 4; ++r)
            Of[((size_t)bh*NSEQ + row0 + 16*w + 4*g + r)*DPH + vt*16 + lr] = o[vt][r]*inv[r];
}

// ---------------------------------------------------------------------------
// Kernel 3: output projection. out[b,i,j,d] = sum_{h,v} att[b,h,pos,v]*wo[d,v,h].
// ---------------------------------------------------------------------------
#define P3 8
__global__ __launch_bounds__(256) void k_oproj(
    const float* __restrict__ att, const float* __restrict__ wo,
    float* __restrict__ out)
{
    __shared__ float asm_[P3][512];   // att, reordered e = v*8+h (matches wo row order)
    __shared__ float wsm[64][68];     // transposed tile [e][d]
    const int tid = threadIdx.x;
    const int pos0 = blockIdx.x * P3;

#pragma unroll
    for (int p = 0; p < P3; ++p) {
        int pos = pos0 + p;
        int b = pos / NSEQ, rem = pos - b*NSEQ;
#pragma unroll
        for (int u = 0; u < 2; ++u) {
            int e = tid + 256*u;
            int h = e & 7, v = e >> 3;
            asm_[p][e] = att[((size_t)(b*NHH + h)*NSEQ + rem)*DPH + v];
        }
    }

    const int pp = tid >> 5, dl = tid & 31;    // position, d-lane
    const int rstg = tid >> 2, fstg = tid & 3; // staging map
    const int pos = pos0 + pp;

    for (int dt = 0; dt < 8; ++dt) {
        float acc0 = 0.f, acc1 = 0.f;
        for (int et = 0; et < 8; ++et) {
            __syncthreads();   // prev tile consumed (also covers asm_ staging)
            const float4* wg = reinterpret_cast<const float4*>(
                wo + (size_t)(dt*64 + rstg)*512 + et*64);
#pragma unroll
            for (int u = 0; u < 4; ++u) {
                float4 w4 = wg[fstg + 4*u];
                int e0 = (fstg + 4*u)*4;
                wsm[e0+0][rstg] = w4.x;
                wsm[e0+1][rstg] = w4.y;
                wsm[e0+2][rstg] = w4.z;
                wsm[e0+3][rstg] = w4.w;
            }
            __syncthreads();
#pragma unroll 16
            for (int ee = 0; ee < 64; ++ee) {
                float a = asm_[pp][et*64 + ee];
                acc0 = fmaf(a, wsm[ee][dl],      acc0);
                acc1 = fmaf(a, wsm[ee][dl+32],   acc1);
            }
        }
        out[(size_t)pos*DD + dt*64 + dl]      = acc0;
        out[(size_t)pos*DD + dt*64 + dl + 32] = acc1;
    }
}

// ---------------------------------------------------------------------------
extern "C" void kernel_launch(void* const* d_in, const int* in_sizes, int n_in,
                              void* d_out, int out_size, void* d_ws, size_t ws_size,
                              hipStream_t stream) {
    const float* x   = (const float*)d_in[0];
    const float* wq  = (const float*)d_in[1];
    const float* wk  = (const float*)d_in[2];
    const float* wv  = (const float*)d_in[3];
    const float* wo  = (const float*)d_in[4];
    const float* ang = (const float*)d_in[5];
    float* out = (float*)d_out;

    const size_t per = (size_t)BB*NHH*NSEQ*DPH;   // 2.36M elems per tensor
    ushort* qb = (ushort*)d_ws;
    ushort* kb = qb + per;
    ushort* vT = kb + per;
    float*  Ob = (float*)(vT + per);              // 14.2 MB offset, 4B aligned

    k_qkv_rope<<<(BB*NSEQ)/P1, 256, 0, stream>>>(x, wq, wk, wv, ang, qb, kb, vT);
    k_attn_mfma<<<BB*NHH*(NSEQ/CK), 256, 0, stream>>>(qb, kb, vT, Ob);
    k_oproj<<<(BB*NSEQ)/P3, 256, 0, stream>>>(Ob, wo, out);
}

// Round 4
// 237.741 us; speedup vs baseline: 4.0000x; 1.9056x over previous
//
#include <hip/hip_runtime.h>
#include <hip/hip_bf16.h>
#include <math.h>

// Problem constants (fixed by setup_inputs)
#define BB   2
#define WW   48
#define DD   512
#define DPH  64
#define NHH  8
#define NSEQ 2304
#define NPOS (BB*NSEQ)      // 4608
#define NXE  (NPOS*DD)      // 2359296
#define WSZ  (DD*DD)        // 262144

typedef __attribute__((ext_vector_type(8))) short short8v;  // 8 bf16
typedef __attribute__((ext_vector_type(4))) float f32x4;

__device__ __forceinline__ ushort f2bf(float f) {
    union { __hip_bfloat16 h; ushort u; } cv;
    cv.h = __float2bfloat16(f);
    return cv.u;
}
__device__ __forceinline__ float bf2f(ushort u) {
    return __uint_as_float(((uint)u) << 16);
}

// ---------------------------------------------------------------------------
// Prep: split-precision bf16 (hi + lo residual) for x and all weight panels.
//   x  -> xh/xl [pos][512]
//   Bq*[c][d] = wq[d, v=c>>3, h=c&7] * 0.125 (exact pow2), Bk*/Bv* unscaled,
//   Bo*[d][e] = wo[d, v=e&63, h=e>>6]   (e = h*64+v matches attention O layout)
// ---------------------------------------------------------------------------
__global__ __launch_bounds__(256) void k_prep(
    const float* __restrict__ x,  const float* __restrict__ wq,
    const float* __restrict__ wk, const float* __restrict__ wv,
    const float* __restrict__ wo,
    ushort* __restrict__ xh, ushort* __restrict__ xl,
    ushort* __restrict__ Bqh, ushort* __restrict__ Bql,
    ushort* __restrict__ Bkh, ushort* __restrict__ Bkl,
    ushort* __restrict__ Bvh, ushort* __restrict__ Bvl,
    ushort* __restrict__ Boh, ushort* __restrict__ Bol)
{
    int idx = blockIdx.x*256 + threadIdx.x;      // grid covers NXE + 4*WSZ exactly
    float s;
    ushort *ph, *pl; int o;
    if (idx < NXE) {
        s = x[idx]; ph = xh; pl = xl; o = idx;
    } else {
        int t = idx - NXE;
        int sel = t >> 18;
        o = t & (WSZ-1);
        int c = o >> 9, k = o & 511;
        if (sel == 0)      { s = wq[k*512 + c] * 0.125f; ph = Bqh; pl = Bql; }
        else if (sel == 1) { s = wk[k*512 + c];          ph = Bkh; pl = Bkl; }
        else if (sel == 2) { s = wv[k*512 + c];          ph = Bvh; pl = Bvl; }
        else               { s = wo[c*512 + ((k&63)<<3) + (k>>6)]; ph = Boh; pl = Bol; }
    }
    ushort hi = f2bf(s);
    ph[o] = hi;
    pl[o] = f2bf(s - bf2f(hi));
}

// ---------------------------------------------------------------------------
// QKV GEMM, split-precision (3 MFMA products), fused RoPE epilogue.
// grid = 3 matrices x 72 row-blocks x 2 col-blocks. Block: 64 rows x 256 cols.
// LDS pitch 80 B per 32-bf16 row (conflict-free for b128 at our access maps).
// ---------------------------------------------------------------------------
#define LPITCH 80
__global__ __launch_bounds__(256) void k_gemm_qkv(
    const ushort* __restrict__ xhp, const ushort* __restrict__ xlp,
    const ushort* __restrict__ Bqh, const ushort* __restrict__ Bql,
    const ushort* __restrict__ Bkh, const ushort* __restrict__ Bkl,
    const ushort* __restrict__ Bvh, const ushort* __restrict__ Bvl,
    const float* __restrict__ ang,
    ushort* __restrict__ qa, ushort* __restrict__ ka, ushort* __restrict__ vT)
{
    __shared__ char xsh[64*LPITCH], xsl[64*LPITCH];
    __shared__ char wsh[256*LPITCH], wsl[256*LPITCH];
    const int tid = threadIdx.x;
    const int w = tid>>6, l = tid&63, g = l>>4, lr = l&15;
    const int mid = blockIdx.x / 144;
    const int rmb = blockIdx.x - mid*144;
    const int rowblk = rmb >> 1, colblk = rmb & 1;
    const int row0 = rowblk*64, col0 = colblk*256;
    const ushort* Bh; const ushort* Bl;
    if (mid==0)      { Bh = Bqh; Bl = Bql; }
    else if (mid==1) { Bh = Bkh; Bl = Bkl; }
    else             { Bh = Bvh; Bl = Bvl; }

    f32x4 acc[4][4];
#pragma unroll
    for (int mt=0;mt<4;++mt)
#pragma unroll
        for (int nt=0;nt<4;++nt) acc[mt][nt] = (f32x4){0.f,0.f,0.f,0.f};

#pragma unroll 1
    for (int kc = 0; kc < 16; ++kc) {
        const int k0 = kc*32;
        __syncthreads();
        // stage A tiles (hi, lo): 512 uint4 total, 2 per thread
#pragma unroll
        for (int u = 0; u < 2; ++u) {
            int i2 = tid + 256*u;
            int tile = i2 >> 8, t2 = i2 & 255;
            int sr = t2 >> 2, sg = t2 & 3;
            const ushort* src = (tile ? xlp : xhp) + (size_t)(row0+sr)*512 + k0 + sg*8;
            char* dst = (tile ? xsl : xsh) + sr*LPITCH + sg*16;
            *reinterpret_cast<uint4*>(dst) = *reinterpret_cast<const uint4*>(src);
        }
        // stage B tiles (hi, lo): 2048 uint4 total, 8 per thread
#pragma unroll
        for (int u = 0; u < 8; ++u) {
            int i2 = tid + 256*u;
            int tile = i2 >> 10, t2 = i2 & 1023;
            int c = t2 >> 2, sg = t2 & 3;
            const ushort* src = (tile ? Bl : Bh) + (size_t)(col0+c)*512 + k0 + sg*8;
            char* dst = (tile ? wsl : wsh) + c*LPITCH + sg*16;
            *reinterpret_cast<uint4*>(dst) = *reinterpret_cast<const uint4*>(src);
        }
        __syncthreads();
        short8v ah[4], al[4], bh_[4], bl_[4];
#pragma unroll
        for (int mt = 0; mt < 4; ++mt) {
            ah[mt] = *reinterpret_cast<const short8v*>(xsh + (mt*16+lr)*LPITCH + g*16);
            al[mt] = *reinterpret_cast<const short8v*>(xsl + (mt*16+lr)*LPITCH + g*16);
        }
#pragma unroll
        for (int nt = 0; nt < 4; ++nt) {
            bh_[nt] = *reinterpret_cast<const short8v*>(wsh + (w*64+nt*16+lr)*LPITCH + g*16);
            bl_[nt] = *reinterpret_cast<const short8v*>(wsl + (w*64+nt*16+lr)*LPITCH + g*16);
        }
#pragma unroll
        for (int mt = 0; mt < 4; ++mt)
#pragma unroll
            for (int nt = 0; nt < 4; ++nt) {
                acc[mt][nt] = __builtin_amdgcn_mfma_f32_16x16x32_bf16(ah[mt], bh_[nt], acc[mt][nt], 0, 0, 0);
                acc[mt][nt] = __builtin_amdgcn_mfma_f32_16x16x32_bf16(ah[mt], bl_[nt], acc[mt][nt], 0, 0, 0);
                acc[mt][nt] = __builtin_amdgcn_mfma_f32_16x16x32_bf16(al[mt], bh_[nt], acc[mt][nt], 0, 0, 0);
            }
    }

    const int b = row0 / NSEQ;
    const int rem0 = row0 - b*NSEQ;
    if (mid < 2) {
        // fused RoPE: pair (v even, v odd) lives in lanes (lr, lr+8); pc lane-uniform
        ushort* dst = (mid==0) ? qa : ka;
        const int sgn = (lr >= 8);
#pragma unroll
        for (int nt = 0; nt < 4; ++nt) {
            int cbase = col0 + w*64 + nt*16;
            int pc = cbase >> 4;
            float a_i = ang[pc], a_j = ang[32 + pc];
            int c = cbase + lr;
            int h = c & 7, v = c >> 3;
            ushort* colbase = dst + ((size_t)(b*NHH + h)*NSEQ)*DPH + v;
#pragma unroll
            for (int mt = 0; mt < 4; ++mt)
#pragma unroll
                for (int r = 0; r < 4; ++r) {
                    int rowrem = rem0 + mt*16 + 4*g + r;
                    int i = rowrem / WW, j = rowrem - (rowrem/WW)*WW;
                    float th = (float)i*a_i + (float)j*a_j;
                    float sn, cn; __sincosf(th, &sn, &cn);
                    float own = acc[mt][nt][r];
                    float oth = __shfl_xor(own, 8);
                    float rot = sgn ? (oth*sn + own*cn) : (own*cn - oth*sn);
                    colbase[(size_t)rowrem*DPH] = f2bf(rot);
                }
        }
    } else {
        // v: store transposed [bh][64][n]
#pragma unroll
        for (int nt = 0; nt < 4; ++nt) {
            int c = col0 + w*64 + nt*16 + lr;
            int h = c & 7, v = c >> 3;
            ushort* colbase = vT + ((size_t)((b*NHH + h)*DPH + v))*NSEQ + rem0;
#pragma unroll
            for (int mt = 0; mt < 4; ++mt)
#pragma unroll
                for (int r = 0; r < 4; ++r)
                    colbase[mt*16 + 4*g + r] = f2bf(acc[mt][nt][r]);
        }
    }
}

// ---------------------------------------------------------------------------
// Output projection GEMM: A = O_att bf16 [pos][e] (single), B = Bo split
// (2 products), fp32 out. Block: 64 rows x 256 cols; grid 72 x 2.
// ---------------------------------------------------------------------------
__global__ __launch_bounds__(256) void k_gemm_o(
    const ushort* __restrict__ Oa, const ushort* __restrict__ Boh,
    const ushort* __restrict__ Bol, float* __restrict__ out)
{
    __shared__ char xs[64*LPITCH];
    __shared__ char wsh[256*LPITCH], wsl[256*LPITCH];
    const int tid = threadIdx.x;
    const int w = tid>>6, l = tid&63, g = l>>4, lr = l&15;
    const int row0 = (blockIdx.x >> 1)*64;
    const int col0 = (blockIdx.x & 1)*256;

    f32x4 acc[4][4];
#pragma unroll
    for (int mt=0;mt<4;++mt)
#pragma unroll
        for (int nt=0;nt<4;++nt) acc[mt][nt] = (f32x4){0.f,0.f,0.f,0.f};

#pragma unroll 1
    for (int kc = 0; kc < 16; ++kc) {
        const int k0 = kc*32;
        __syncthreads();
        {   // stage A tile: 256 uint4, 1 per thread
            int sr = tid >> 2, sg = tid & 3;
            *reinterpret_cast<uint4*>(xs + sr*LPITCH + sg*16) =
                *reinterpret_cast<const uint4*>(Oa + (size_t)(row0+sr)*512 + k0 + sg*8);
        }
#pragma unroll
        for (int u = 0; u < 8; ++u) {   // stage B tiles (hi, lo)
            int i2 = tid + 256*u;
            int tile = i2 >> 10, t2 = i2 & 1023;
            int c = t2 >> 2, sg = t2 & 3;
            const ushort* src = (tile ? Bol : Boh) + (size_t)(col0+c)*512 + k0 + sg*8;
            char* dst = (tile ? wsl : wsh) + c*LPITCH + sg*16;
            *reinterpret_cast<uint4*>(dst) = *reinterpret_cast<const uint4*>(src);
        }
        __syncthreads();
        short8v a[4], bh_[4], bl_[4];
#pragma unroll
        for (int mt = 0; mt < 4; ++mt)
            a[mt] = *reinterpret_cast<const short8v*>(xs + (mt*16+lr)*LPITCH + g*16);
#pragma unroll
        for (int nt = 0; nt < 4; ++nt) {
            bh_[nt] = *reinterpret_cast<const short8v*>(wsh + (w*64+nt*16+lr)*LPITCH + g*16);
            bl_[nt] = *reinterpret_cast<const short8v*>(wsl + (w*64+nt*16+lr)*LPITCH + g*16);
        }
#pragma unroll
        for (int mt = 0; mt < 4; ++mt)
#pragma unroll
            for (int nt = 0; nt < 4; ++nt) {
                acc[mt][nt] = __builtin_amdgcn_mfma_f32_16x16x32_bf16(a[mt], bh_[nt], acc[mt][nt], 0, 0, 0);
                acc[mt][nt] = __builtin_amdgcn_mfma_f32_16x16x32_bf16(a[mt], bl_[nt], acc[mt][nt], 0, 0, 0);
            }
    }

#pragma unroll
    for (int mt=0;mt<4;++mt)
#pragma unroll
        for (int r=0;r<4;++r) {
            float* rowp = out + (size_t)(row0 + mt*16 + 4*g + r)*DD + col0 + w*64;
#pragma unroll
            for (int nt=0;nt<4;++nt)
                rowp[nt*16 + lr] = acc[mt][nt][r];
        }
}

// ---------------------------------------------------------------------------
// Flash attention, bf16 MFMA (16x16x32). O stored bf16 as [pos][e=h*64+v].
// ---------------------------------------------------------------------------
#define CK 64
#define NCHUNK (NSEQ/CK)   // 36
#define KP 72              // LDS pitch (bf16 elems) -> 144 B rows
__global__ __launch_bounds__(256) void k_attn_mfma(
    const ushort* __restrict__ qb, const ushort* __restrict__ kb,
    const ushort* __restrict__ vb, ushort* __restrict__ Oa)
{
    __shared__ ushort ksm[CK][KP];
    __shared__ ushort vsm[CK][KP];
    __shared__ ushort psm[4][16][KP];
    const int tid = threadIdx.x;
    const int w = tid >> 6, l = tid & 63;
    const int g = l >> 4, lr = l & 15;
    const int bh   = blockIdx.x / (NSEQ/64);
    const int qc   = blockIdx.x - bh*(NSEQ/64);
    const int row0 = qc * 64;
    const ushort* kbase = kb + (size_t)bh*NSEQ*DPH;
    const ushort* vbase = vb + (size_t)bh*DPH*NSEQ;

    const ushort* qptr = qb + ((size_t)bh*NSEQ + row0 + 16*w + lr)*DPH + g*8;
    const short8v qA0 = *reinterpret_cast<const short8v*>(qptr);
    const short8v qA1 = *reinterpret_cast<const short8v*>(qptr + 32);

    float mrow[4], lrow[4];
    f32x4 o[4];
#pragma unroll
    for (int r = 0; r < 4; ++r) { mrow[r] = -INFINITY; lrow[r] = 0.f; }
#pragma unroll
    for (int vt = 0; vt < 4; ++vt) o[vt] = (f32x4){0.f,0.f,0.f,0.f};

    for (int t = 0; t < NCHUNK; ++t) {
        __syncthreads();
#pragma unroll
        for (int i = 0; i < 2; ++i) {
            int tau = tid + 256*i;
            int row = tau >> 3, cg = tau & 7;
            *reinterpret_cast<uint4*>(&ksm[row][cg*8]) =
                *reinterpret_cast<const uint4*>(kbase + ((size_t)(t*CK + row))*DPH + cg*8);
            *reinterpret_cast<uint4*>(&vsm[row][cg*8]) =
                *reinterpret_cast<const uint4*>(vbase + (size_t)row*NSEQ + t*CK + cg*8);
        }
        __syncthreads();

        f32x4 s[4];
#pragma unroll
        for (int tile = 0; tile < 4; ++tile) {
            short8v k0 = *reinterpret_cast<const short8v*>(&ksm[tile*16 + lr][g*8]);
            short8v k1 = *reinterpret_cast<const short8v*>(&ksm[tile*16 + lr][32 + g*8]);
            f32x4 a2 = (f32x4){0.f,0.f,0.f,0.f};
            a2 = __builtin_amdgcn_mfma_f32_16x16x32_bf16(qA0, k0, a2, 0, 0, 0);
            a2 = __builtin_amdgcn_mfma_f32_16x16x32_bf16(qA1, k1, a2, 0, 0, 0);
            s[tile] = a2;
        }

        float f_r[4];
#pragma unroll
        for (int r = 0; r < 4; ++r) {
            float cm = fmaxf(fmaxf(s[0][r], s[1][r]), fmaxf(s[2][r], s[3][r]));
#pragma unroll
            for (int msk = 8; msk >= 1; msk >>= 1)
                cm = fmaxf(cm, __shfl_xor(cm, msk));
            float mn = fmaxf(mrow[r], cm);
            f_r[r] = __expf(mrow[r] - mn);
            mrow[r] = mn;
            float rs = 0.f;
#pragma unroll
            for (int tile = 0; tile < 4; ++tile) {
                float p = __expf(s[tile][r] - mn);
                s[tile][r] = p;
                rs += p;
            }
#pragma unroll
            for (int msk = 8; msk >= 1; msk >>= 1)
                rs += __shfl_xor(rs, msk);
            lrow[r] = lrow[r]*f_r[r] + rs;
        }

#pragma unroll
        for (int tile = 0; tile < 4; ++tile)
#pragma unroll
            for (int r = 0; r < 4; ++r)
                psm[w][4*g + r][lr + 16*tile] = f2bf(s[tile][r]);

#pragma unroll
        for (int vt = 0; vt < 4; ++vt)
#pragma unroll
            for (int r = 0; r < 4; ++r)
                o[vt][r] *= f_r[r];

#pragma unroll
        for (int half = 0; half < 2; ++half) {
            short8v pA = *reinterpret_cast<const short8v*>(&psm[w][lr][32*half + g*8]);
#pragma unroll
            for (int vt = 0; vt < 4; ++vt) {
                short8v vf = *reinterpret_cast<const short8v*>(&vsm[vt*16 + lr][32*half + g*8]);
                o[vt] = __builtin_amdgcn_mfma_f32_16x16x32_bf16(pA, vf, o[vt], 0, 0, 0);
            }
        }
    }

    float inv[4];
#pragma unroll
    for (int r = 0; r < 4; ++r) inv[r] = 1.f / lrow[r];
    const int b_ = bh >> 3, h_ = bh & 7;
#pragma unroll
    for (int vt = 0; vt < 4; ++vt)
#pragma unroll
        for (int r = 0; r < 4; ++r)
            Oa[((size_t)(b_*NSEQ + row0 + 16*w + 4*g + r))*DD + h_*64 + vt*16 + lr]
                = f2bf(o[vt][r]*inv[r]);
}

// ---------------------------------------------------------------------------
extern "C" void kernel_launch(void* const* d_in, const int* in_sizes, int n_in,
                              void* d_out, int out_size, void* d_ws, size_t ws_size,
                              hipStream_t stream) {
    const float* x   = (const float*)d_in[0];
    const float* wq  = (const float*)d_in[1];
    const float* wk  = (const float*)d_in[2];
    const float* wv  = (const float*)d_in[3];
    const float* wo  = (const float*)d_in[4];
    const float* ang = (const float*)d_in[5];
    float* out = (float*)d_out;

    ushort* xh  = (ushort*)d_ws;         // [4608][512]
    ushort* xl  = xh + NXE;
    ushort* Bqh = xl + NXE;              // 8 x [512][512]
    ushort* Bql = Bqh + WSZ;
    ushort* Bkh = Bql + WSZ;
    ushort* Bkl = Bkh + WSZ;
    ushort* Bvh = Bkl + WSZ;
    ushort* Bvl = Bvh + WSZ;
    ushort* Boh = Bvl + WSZ;
    ushort* Bol = Boh + WSZ;
    ushort* qa  = Bol + WSZ;             // [16][2304][64]
    ushort* ka  = qa + NXE;
    ushort* vT  = ka + NXE;
    ushort* Oa  = xh;                    // alias: x split dead after k_gemm_qkv

    k_prep<<<(NXE + 4*WSZ)/256, 256, 0, stream>>>(x, wq, wk, wv, wo,
        xh, xl, Bqh, Bql, Bkh, Bkl, Bvh, Bvl, Boh, Bol);
    k_gemm_qkv<<<432, 256, 0, stream>>>(xh, xl, Bqh, Bql, Bkh, Bkl, Bvh, Bvl,
        ang, qa, ka, vT);
    k_attn_mfma<<<BB*NHH*(NSEQ/CK), 256, 0, stream>>>(qa, ka, vT, Oa);
    k_gemm_o<<<144, 256, 0, stream>>>(Oa, Boh, Bol, out);
}

// Round 7
// 224.686 us; speedup vs baseline: 4.2324x; 1.0581x over previous
//
#include <hip/hip_runtime.h>
#include <hip/hip_bf16.h>
#include <math.h>

// Problem constants (fixed by setup_inputs)
#define BB   2
#define WW   48
#define DD   512
#define DPH  64
#define NHH  8
#define NSEQ 2304
#define NPOS (BB*NSEQ)      // 4608
#define NXE  (NPOS*DD)      // 2359296
#define WSZ  (DD*DD)        // 262144
#define NROWS (BB*NHH*NSEQ) // 36864 attention rows

typedef __attribute__((ext_vector_type(8))) short short8v;  // 8 bf16
typedef __attribute__((ext_vector_type(4))) float f32x4;

__device__ __forceinline__ ushort f2bf(float f) {
    union { __hip_bfloat16 h; ushort u; } cv;
    cv.h = __float2bfloat16(f);
    return cv.u;
}
__device__ __forceinline__ float bf2f(ushort u) {
    return __uint_as_float(((uint)u) << 16);
}

// ---------------------------------------------------------------------------
// Prep: split-precision bf16 (hi + lo residual) for x and all weight panels.
// ---------------------------------------------------------------------------
__global__ __launch_bounds__(256) void k_prep(
    const float* __restrict__ x,  const float* __restrict__ wq,
    const float* __restrict__ wk, const float* __restrict__ wv,
    const float* __restrict__ wo,
    ushort* __restrict__ xh, ushort* __restrict__ xl,
    ushort* __restrict__ Bqh, ushort* __restrict__ Bql,
    ushort* __restrict__ Bkh, ushort* __restrict__ Bkl,
    ushort* __restrict__ Bvh, ushort* __restrict__ Bvl,
    ushort* __restrict__ Boh, ushort* __restrict__ Bol)
{
    int idx = blockIdx.x*256 + threadIdx.x;      // grid covers NXE + 4*WSZ exactly
    float s;
    ushort *ph, *pl; int o;
    if (idx < NXE) {
        s = x[idx]; ph = xh; pl = xl; o = idx;
    } else {
        int t = idx - NXE;
        int sel = t >> 18;
        o = t & (WSZ-1);
        int c = o >> 9, k = o & 511;
        if (sel == 0)      { s = wq[k*512 + c] * 0.125f; ph = Bqh; pl = Bql; }
        else if (sel == 1) { s = wk[k*512 + c];          ph = Bkh; pl = Bkl; }
        else if (sel == 2) { s = wv[k*512 + c];          ph = Bvh; pl = Bvl; }
        else               { s = wo[c*512 + ((k&63)<<3) + (k>>6)]; ph = Boh; pl = Bol; }
    }
    ushort hi = f2bf(s);
    ph[o] = hi;
    pl[o] = f2bf(s - bf2f(hi));
}

// ---------------------------------------------------------------------------
// QKV GEMM, split-precision (3 MFMA products), fused RoPE epilogue.
// ---------------------------------------------------------------------------
#define LPITCH 80
__global__ __launch_bounds__(256) void k_gemm_qkv(
    const ushort* __restrict__ xhp, const ushort* __restrict__ xlp,
    const ushort* __restrict__ Bqh, const ushort* __restrict__ Bql,
    const ushort* __restrict__ Bkh, const ushort* __restrict__ Bkl,
    const ushort* __restrict__ Bvh, const ushort* __restrict__ Bvl,
    const float* __restrict__ ang,
    ushort* __restrict__ qa, ushort* __restrict__ ka, ushort* __restrict__ vT)
{
    __shared__ char xsh[64*LPITCH], xsl[64*LPITCH];
    __shared__ char wsh[256*LPITCH], wsl[256*LPITCH];
    const int tid = threadIdx.x;
    const int w = tid>>6, l = tid&63, g = l>>4, lr = l&15;
    const int mid = blockIdx.x / 144;
    const int rmb = blockIdx.x - mid*144;
    const int rowblk = rmb >> 1, colblk = rmb & 1;
    const int row0 = rowblk*64, col0 = colblk*256;
    const ushort* Bh; const ushort* Bl;
    if (mid==0)      { Bh = Bqh; Bl = Bql; }
    else if (mid==1) { Bh = Bkh; Bl = Bkl; }
    else             { Bh = Bvh; Bl = Bvl; }

    f32x4 acc[4][4];
#pragma unroll
    for (int mt=0;mt<4;++mt)
#pragma unroll
        for (int nt=0;nt<4;++nt) acc[mt][nt] = (f32x4){0.f,0.f,0.f,0.f};

#pragma unroll 1
    for (int kc = 0; kc < 16; ++kc) {
        const int k0 = kc*32;
        __syncthreads();
#pragma unroll
        for (int u = 0; u < 2; ++u) {
            int i2 = tid + 256*u;
            int tile = i2 >> 8, t2 = i2 & 255;
            int sr = t2 >> 2, sg = t2 & 3;
            const ushort* src = (tile ? xlp : xhp) + (size_t)(row0+sr)*512 + k0 + sg*8;
            char* dst = (tile ? xsl : xsh) + sr*LPITCH + sg*16;
            *reinterpret_cast<uint4*>(dst) = *reinterpret_cast<const uint4*>(src);
        }
#pragma unroll
        for (int u = 0; u < 8; ++u) {
            int i2 = tid + 256*u;
            int tile = i2 >> 10, t2 = i2 & 1023;
            int c = t2 >> 2, sg = t2 & 3;
            const ushort* src = (tile ? Bl : Bh) + (size_t)(col0+c)*512 + k0 + sg*8;
            char* dst = (tile ? wsl : wsh) + c*LPITCH + sg*16;
            *reinterpret_cast<uint4*>(dst) = *reinterpret_cast<const uint4*>(src);
        }
        __syncthreads();
        short8v ah[4], al[4], bh_[4], bl_[4];
#pragma unroll
        for (int mt = 0; mt < 4; ++mt) {
            ah[mt] = *reinterpret_cast<const short8v*>(xsh + (mt*16+lr)*LPITCH + g*16);
            al[mt] = *reinterpret_cast<const short8v*>(xsl + (mt*16+lr)*LPITCH + g*16);
        }
#pragma unroll
        for (int nt = 0; nt < 4; ++nt) {
            bh_[nt] = *reinterpret_cast<const short8v*>(wsh + (w*64+nt*16+lr)*LPITCH + g*16);
            bl_[nt] = *reinterpret_cast<const short8v*>(wsl + (w*64+nt*16+lr)*LPITCH + g*16);
        }
#pragma unroll
        for (int mt = 0; mt < 4; ++mt)
#pragma unroll
            for (int nt = 0; nt < 4; ++nt) {
                acc[mt][nt] = __builtin_amdgcn_mfma_f32_16x16x32_bf16(ah[mt], bh_[nt], acc[mt][nt], 0, 0, 0);
                acc[mt][nt] = __builtin_amdgcn_mfma_f32_16x16x32_bf16(ah[mt], bl_[nt], acc[mt][nt], 0, 0, 0);
                acc[mt][nt] = __builtin_amdgcn_mfma_f32_16x16x32_bf16(al[mt], bh_[nt], acc[mt][nt], 0, 0, 0);
            }
    }

    const int b = row0 / NSEQ;
    const int rem0 = row0 - b*NSEQ;
    if (mid < 2) {
        ushort* dst = (mid==0) ? qa : ka;
        const int sgn = (lr >= 8);
#pragma unroll
        for (int nt = 0; nt < 4; ++nt) {
            int cbase = col0 + w*64 + nt*16;
            int pc = cbase >> 4;
            float a_i = ang[pc], a_j = ang[32 + pc];
            int c = cbase + lr;
            int h = c & 7, v = c >> 3;
            ushort* colbase = dst + ((size_t)(b*NHH + h)*NSEQ)*DPH + v;
#pragma unroll
            for (int mt = 0; mt < 4; ++mt)
#pragma unroll
                for (int r = 0; r < 4; ++r) {
                    int rowrem = rem0 + mt*16 + 4*g + r;
                    int i = rowrem / WW, j = rowrem - (rowrem/WW)*WW;
                    float th = (float)i*a_i + (float)j*a_j;
                    float sn, cn; __sincosf(th, &sn, &cn);
                    float own = acc[mt][nt][r];
                    float oth = __shfl_xor(own, 8);
                    float rot = sgn ? (oth*sn + own*cn) : (own*cn - oth*sn);
                    colbase[(size_t)rowrem*DPH] = f2bf(rot);
                }
        }
    } else {
#pragma unroll
        for (int nt = 0; nt < 4; ++nt) {
            int c = col0 + w*64 + nt*16 + lr;
            int h = c & 7, v = c >> 3;
            ushort* colbase = vT + ((size_t)((b*NHH + h)*DPH + v))*NSEQ + rem0;
#pragma unroll
            for (int mt = 0; mt < 4; ++mt)
#pragma unroll
                for (int r = 0; r < 4; ++r)
                    colbase[mt*16 + 4*g + r] = f2bf(acc[mt][nt][r]);
        }
    }
}

// ---------------------------------------------------------------------------
// Output projection GEMM: A = O_att bf16 [pos][e] (single), B = Bo split.
// ---------------------------------------------------------------------------
__global__ __launch_bounds__(256) void k_gemm_o(
    const ushort* __restrict__ Oa, const ushort* __restrict__ Boh,
    const ushort* __restrict__ Bol, float* __restrict__ out)
{
    __shared__ char xs[64*LPITCH];
    __shared__ char wsh[256*LPITCH], wsl[256*LPITCH];
    const int tid = threadIdx.x;
    const int w = tid>>6, l = tid&63, g = l>>4, lr = l&15;
    const int row0 = (blockIdx.x >> 1)*64;
    const int col0 = (blockIdx.x & 1)*256;

    f32x4 acc[4][4];
#pragma unroll
    for (int mt=0;mt<4;++mt)
#pragma unroll
        for (int nt=0;nt<4;++nt) acc[mt][nt] = (f32x4){0.f,0.f,0.f,0.f};

#pragma unroll 1
    for (int kc = 0; kc < 16; ++kc) {
        const int k0 = kc*32;
        __syncthreads();
        {
            int sr = tid >> 2, sg = tid & 3;
            *reinterpret_cast<uint4*>(xs + sr*LPITCH + sg*16) =
                *reinterpret_cast<const uint4*>(Oa + (size_t)(row0+sr)*512 + k0 + sg*8);
        }
#pragma unroll
        for (int u = 0; u < 8; ++u) {
            int i2 = tid + 256*u;
            int tile = i2 >> 10, t2 = i2 & 1023;
            int c = t2 >> 2, sg = t2 & 3;
            const ushort* src = (tile ? Bol : Boh) + (size_t)(col0+c)*512 + k0 + sg*8;
            char* dst = (tile ? wsl : wsh) + c*LPITCH + sg*16;
            *reinterpret_cast<uint4*>(dst) = *reinterpret_cast<const uint4*>(src);
        }
        __syncthreads();
        short8v a[4], bh_[4], bl_[4];
#pragma unroll
        for (int mt = 0; mt < 4; ++mt)
            a[mt] = *reinterpret_cast<const short8v*>(xs + (mt*16+lr)*LPITCH + g*16);
#pragma unroll
        for (int nt = 0; nt < 4; ++nt) {
            bh_[nt] = *reinterpret_cast<const short8v*>(wsh + (w*64+nt*16+lr)*LPITCH + g*16);
            bl_[nt] = *reinterpret_cast<const short8v*>(wsl + (w*64+nt*16+lr)*LPITCH + g*16);
        }
#pragma unroll
        for (int mt = 0; mt < 4; ++mt)
#pragma unroll
            for (int nt = 0; nt < 4; ++nt) {
                acc[mt][nt] = __builtin_amdgcn_mfma_f32_16x16x32_bf16(a[mt], bh_[nt], acc[mt][nt], 0, 0, 0);
                acc[mt][nt] = __builtin_amdgcn_mfma_f32_16x16x32_bf16(a[mt], bl_[nt], acc[mt][nt], 0, 0, 0);
            }
    }

#pragma unroll
    for (int mt=0;mt<4;++mt)
#pragma unroll
        for (int r=0;r<4;++r) {
            float* rowp = out + (size_t)(row0 + mt*16 + 4*g + r)*DD + col0 + w*64;
#pragma unroll
            for (int nt=0;nt<4;++nt)
                rowp[nt*16 + lr] = acc[mt][nt][r];
        }
}

// ---------------------------------------------------------------------------
// Flash attention, bf16 MFMA, split-KV (2 splits of 18 chunks).
// Writes unnormalized partial O (bf16) + per-row (m, l).
// psm XOR-swizzled (byte ^= (row>>2)<<5) to kill P-staging bank conflicts.
// ---------------------------------------------------------------------------
#define CK 64
#define KP 72              // ksm/vsm pitch (bf16 elems) -> 144 B rows
__global__ __launch_bounds__(256) void k_attn_mfma(
    const ushort* __restrict__ qb, const ushort* __restrict__ kb,
    const ushort* __restrict__ vb, ushort* __restrict__ Op,
    float2* __restrict__ mlp)
{
    __shared__ ushort ksm[CK][KP];
    __shared__ ushort vsm[CK][KP];
    __shared__ char psmb[4][2304];       // per-wave 16x64 bf16, pitch 144B, swizzled
    const int tid = threadIdx.x;
    const int w = tid >> 6, l = tid & 63;
    const int g = l >> 4, lr = l & 15;
    const int sp  = blockIdx.x / 576;
    const int rest = blockIdx.x - sp*576;
    const int bh = rest / 36;
    const int qc = rest - bh*36;
    const int row0 = qc * 64;
    const ushort* kbase = kb + (size_t)bh*NSEQ*DPH;
    const ushort* vbase = vb + (size_t)bh*DPH*NSEQ;

    const ushort* qptr = qb + ((size_t)bh*NSEQ + row0 + 16*w + lr)*DPH + g*8;
    const short8v qA0 = *reinterpret_cast<const short8v*>(qptr);
    const short8v qA1 = *reinterpret_cast<const short8v*>(qptr + 32);

    float mrow[4], lrow[4];
    f32x4 o[4];
#pragma unroll
    for (int r = 0; r < 4; ++r) { mrow[r] = -INFINITY; lrow[r] = 0.f; }
#pragma unroll
    for (int vt = 0; vt < 4; ++vt) o[vt] = (f32x4){0.f,0.f,0.f,0.f};

    for (int t = sp*18; t < sp*18 + 18; ++t) {
        __syncthreads();
#pragma unroll
        for (int i = 0; i < 2; ++i) {
            int tau = tid + 256*i;
            int row = tau >> 3, cg = tau & 7;
            *reinterpret_cast<uint4*>(&ksm[row][cg*8]) =
                *reinterpret_cast<const uint4*>(kbase + ((size_t)(t*CK + row))*DPH + cg*8);
            *reinterpret_cast<uint4*>(&vsm[row][cg*8]) =
                *reinterpret_cast<const uint4*>(vbase + (size_t)row*NSEQ + t*CK + cg*8);
        }
        __syncthreads();

        f32x4 sc[4];
#pragma unroll
        for (int tile = 0; tile < 4; ++tile) {
            short8v k0 = *reinterpret_cast<const short8v*>(&ksm[tile*16 + lr][g*8]);
            short8v k1 = *reinterpret_cast<const short8v*>(&ksm[tile*16 + lr][32 + g*8]);
            f32x4 a2 = (f32x4){0.f,0.f,0.f,0.f};
            a2 = __builtin_amdgcn_mfma_f32_16x16x32_bf16(qA0, k0, a2, 0, 0, 0);
            a2 = __builtin_amdgcn_mfma_f32_16x16x32_bf16(qA1, k1, a2, 0, 0, 0);
            sc[tile] = a2;
        }

        float f_r[4];
#pragma unroll
        for (int r = 0; r < 4; ++r) {
            float cm = fmaxf(fmaxf(sc[0][r], sc[1][r]), fmaxf(sc[2][r], sc[3][r]));
#pragma unroll
            for (int msk = 8; msk >= 1; msk >>= 1)
                cm = fmaxf(cm, __shfl_xor(cm, msk));
            float mn = fmaxf(mrow[r], cm);
            f_r[r] = __expf(mrow[r] - mn);
            mrow[r] = mn;
            float rs = 0.f;
#pragma unroll
            for (int tile = 0; tile < 4; ++tile) {
                float p = __expf(sc[tile][r] - mn);
                sc[tile][r] = p;
                rs += p;
            }
#pragma unroll
            for (int msk = 8; msk >= 1; msk >>= 1)
                rs += __shfl_xor(rs, msk);
            lrow[r] = lrow[r]*f_r[r] + rs;
        }

        // P (D-layout) -> swizzled LDS bf16
#pragma unroll
        for (int tile = 0; tile < 4; ++tile)
#pragma unroll
            for (int r = 0; r < 4; ++r) {
                int bo = (((4*g + r)*144) + (lr + 16*tile)*2) ^ (g << 5);
                *reinterpret_cast<ushort*>(&psmb[w][bo]) = f2bf(sc[tile][r]);
            }

#pragma unroll
        for (int vt = 0; vt < 4; ++vt)
#pragma unroll
            for (int r = 0; r < 4; ++r)
                o[vt][r] *= f_r[r];

#pragma unroll
        for (int half = 0; half < 2; ++half) {
            int bo = (lr*144 + 64*half + 16*g) ^ (((lr >> 2) & 3) << 5);
            short8v pA = *reinterpret_cast<const short8v*>(&psmb[w][bo]);
#pragma unroll
            for (int vt = 0; vt < 4; ++vt) {
                short8v vf = *reinterpret_cast<const short8v*>(&vsm[vt*16 + lr][32*half + g*8]);
                o[vt] = __builtin_amdgcn_mfma_f32_16x16x32_bf16(pA, vf, o[vt], 0, 0, 0);
            }
        }
    }

    // ---- store unnormalized partial O (bf16) + (m,l) per row
    ushort* obase = Op + ((size_t)sp*NROWS + (size_t)bh*NSEQ + row0 + 16*w)*64;
#pragma unroll
    for (int vt = 0; vt < 4; ++vt)
#pragma unroll
        for (int r = 0; r < 4; ++r)
            obase[(4*g + r)*64 + vt*16 + lr] = f2bf(o[vt][r]);
    if (lr == 0) {
#pragma unroll
        for (int r = 0; r < 4; ++r)
            mlp[sp*NROWS + bh*NSEQ + row0 + 16*w + 4*g + r] = make_float2(mrow[r], lrow[r]);
    }
}

// ---------------------------------------------------------------------------
// Combine the 2 KV-splits: O = (O0*e^{m0-M} + O1*e^{m1-M}) / (l0*e^{m0-M}+l1*e^{m1-M})
// Writes bf16 Oa[pos][e = h*64+v] for the output GEMM.
// ---------------------------------------------------------------------------
__global__ __launch_bounds__(256) void k_combine(
    const ushort* __restrict__ Op, const float2* __restrict__ mlp,
    ushort* __restrict__ Oa)
{
    const int tid = threadIdx.x;
    const int row = blockIdx.x*32 + (tid >> 3);
    const int c8 = (tid & 7)*8;
    float2 a = mlp[row], b = mlp[NROWS + row];
    float M = fmaxf(a.x, b.x);
    float w0 = __expf(a.x - M), w1 = __expf(b.x - M);
    float inv = 1.f / (a.y*w0 + b.y*w1);
    const ushort* p0 = Op + (size_t)row*64 + c8;
    const ushort* p1 = p0 + (size_t)NROWS*64;
    uint4 u0 = *reinterpret_cast<const uint4*>(p0);
    uint4 u1 = *reinterpret_cast<const uint4*>(p1);
    const ushort* s0 = reinterpret_cast<const ushort*>(&u0);
    const ushort* s1 = reinterpret_cast<const ushort*>(&u1);
    ushort res[8];
#pragma unroll
    for (int i = 0; i < 8; ++i)
        res[i] = f2bf((bf2f(s0[i])*w0 + bf2f(s1[i])*w1) * inv);
    int bh = row / NSEQ, n = row - bh*NSEQ;
    int b_ = bh >> 3, h_ = bh & 7;
    ushort* dst = Oa + ((size_t)(b_*NSEQ + n))*DD + h_*64 + c8;
    *reinterpret_cast<uint4*>(dst) = *reinterpret_cast<const uint4*>(res);
}

// ---------------------------------------------------------------------------
extern "C" void kernel_launch(void* const* d_in, const int* in_sizes, int n_in,
                              void* d_out, int out_size, void* d_ws, size_t ws_size,
                              hipStream_t stream) {
    const float* x   = (const float*)d_in[0];
    const float* wq  = (const float*)d_in[1];
    const float* wk  = (const float*)d_in[2];
    const float* wv  = (const float*)d_in[3];
    const float* wo  = (const float*)d_in[4];
    const float* ang = (const float*)d_in[5];
    float* out = (float*)d_out;

    ushort* xh  = (ushort*)d_ws;         // [4608][512]; aliased as Op[0..1] after qkv
    ushort* xl  = xh + NXE;
    ushort* Bqh = xl + NXE;              // 8 x [512][512]
    ushort* Bql = Bqh + WSZ;
    ushort* Bkh = Bql + WSZ;
    ushort* Bkl = Bkh + WSZ;
    ushort* Bvh = Bkl + WSZ;
    ushort* Bvl = Bvh + WSZ;
    ushort* Boh = Bvl + WSZ;
    ushort* Bol = Boh + WSZ;
    ushort* qa  = Bol + WSZ;             // [16][2304][64]
    ushort* ka  = qa + NXE;
    ushort* vT  = ka + NXE;
    ushort* Oa  = vT + NXE;              // [4608][512] bf16 (same as round 4)
    ushort* Op  = xh;                    // [2][36864][64] partial O (aliases x splits)
    float2* mlp = (float2*)Bqh;          // [2][36864] (aliases dead Bq panels)

    k_prep<<<(NXE + 4*WSZ)/256, 256, 0, stream>>>(x, wq, wk, wv, wo,
        xh, xl, Bqh, Bql, Bkh, Bkl, Bvh, Bvl, Boh, Bol);
    k_gemm_qkv<<<432, 256, 0, stream>>>(xh, xl, Bqh, Bql, Bkh, Bkl, Bvh, Bvl,
        ang, qa, ka, vT);
    k_attn_mfma<<<1152, 256, 0, stream>>>(qa, ka, vT, Op, mlp);
    k_combine<<<NROWS/32, 256, 0, stream>>>(Op, mlp, Oa);
    k_gemm_o<<<144, 256, 0, stream>>>(Oa, Boh, Bol, out);
}

// Round 9
// 200.271 us; speedup vs baseline: 4.7484x; 1.1219x over previous
//
#include <hip/hip_runtime.h>
#include <hip/hip_bf16.h>
#include <math.h>

// Problem constants (fixed by setup_inputs)
#define BB   2
#define WW   48
#define DD   512
#define DPH  64
#define NHH  8
#define NSEQ 2304
#define NPOS (BB*NSEQ)      // 4608
#define NXE  (NPOS*DD)      // 2359296
#define WSZ  (DD*DD)        // 262144
#define NROWS (BB*NHH*NSEQ) // 36864 attention rows

typedef __attribute__((ext_vector_type(8))) short short8v;  // 8 bf16
typedef __attribute__((ext_vector_type(4))) float f32x4;

__device__ __forceinline__ ushort f2bf(float f) {
    union { __hip_bfloat16 h; ushort u; } cv;
    cv.h = __float2bfloat16(f);
    return cv.u;
}
__device__ __forceinline__ float bf2f(ushort u) {
    return __uint_as_float(((uint)u) << 16);
}
__device__ __forceinline__ uint pack2bf(float lo, float hi) {
    return (uint)f2bf(lo) | ((uint)f2bf(hi) << 16);
}

// ---------------------------------------------------------------------------
// Prep: split-precision bf16 (hi + lo residual) for x and all weight panels.
// ---------------------------------------------------------------------------
__global__ __launch_bounds__(256) void k_prep(
    const float* __restrict__ x,  const float* __restrict__ wq,
    const float* __restrict__ wk, const float* __restrict__ wv,
    const float* __restrict__ wo,
    ushort* __restrict__ xh, ushort* __restrict__ xl,
    ushort* __restrict__ Bqh, ushort* __restrict__ Bql,
    ushort* __restrict__ Bkh, ushort* __restrict__ Bkl,
    ushort* __restrict__ Bvh, ushort* __restrict__ Bvl,
    ushort* __restrict__ Boh, ushort* __restrict__ Bol)
{
    int idx = blockIdx.x*256 + threadIdx.x;      // grid covers NXE + 4*WSZ exactly
    float s;
    ushort *ph, *pl; int o;
    if (idx < NXE) {
        s = x[idx]; ph = xh; pl = xl; o = idx;
    } else {
        int t = idx - NXE;
        int sel = t >> 18;
        o = t & (WSZ-1);
        int c = o >> 9, k = o & 511;
        if (sel == 0)      { s = wq[k*512 + c] * 0.125f; ph = Bqh; pl = Bql; }
        else if (sel == 1) { s = wk[k*512 + c];          ph = Bkh; pl = Bkl; }
        else if (sel == 2) { s = wv[k*512 + c];          ph = Bvh; pl = Bvl; }
        else               { s = wo[c*512 + ((k&63)<<3) + (k>>6)]; ph = Boh; pl = Bol; }
    }
    ushort hi = f2bf(s);
    ph[o] = hi;
    pl[o] = f2bf(s - bf2f(hi));
}

// ---------------------------------------------------------------------------
// QKV GEMM, split-precision (3 MFMA products), fused RoPE epilogue.
// ---------------------------------------------------------------------------
#define LPITCH 80
__global__ __launch_bounds__(256) void k_gemm_qkv(
    const ushort* __restrict__ xhp, const ushort* __restrict__ xlp,
    const ushort* __restrict__ Bqh, const ushort* __restrict__ Bql,
    const ushort* __restrict__ Bkh, const ushort* __restrict__ Bkl,
    const ushort* __restrict__ Bvh, const ushort* __restrict__ Bvl,
    const float* __restrict__ ang,
    ushort* __restrict__ qa, ushort* __restrict__ ka, ushort* __restrict__ vT)
{
    __shared__ char xsh[64*LPITCH], xsl[64*LPITCH];
    __shared__ char wsh[256*LPITCH], wsl[256*LPITCH];
    const int tid = threadIdx.x;
    const int w = tid>>6, l = tid&63, g = l>>4, lr = l&15;
    const int mid = blockIdx.x / 144;
    const int rmb = blockIdx.x - mid*144;
    const int rowblk = rmb >> 1, colblk = rmb & 1;
    const int row0 = rowblk*64, col0 = colblk*256;
    const ushort* Bh; const ushort* Bl;
    if (mid==0)      { Bh = Bqh; Bl = Bql; }
    else if (mid==1) { Bh = Bkh; Bl = Bkl; }
    else             { Bh = Bvh; Bl = Bvl; }

    f32x4 acc[4][4];
#pragma unroll
    for (int mt=0;mt<4;++mt)
#pragma unroll
        for (int nt=0;nt<4;++nt) acc[mt][nt] = (f32x4){0.f,0.f,0.f,0.f};

#pragma unroll 1
    for (int kc = 0; kc < 16; ++kc) {
        const int k0 = kc*32;
        __syncthreads();
#pragma unroll
        for (int u = 0; u < 2; ++u) {
            int i2 = tid + 256*u;
            int tile = i2 >> 8, t2 = i2 & 255;
            int sr = t2 >> 2, sg = t2 & 3;
            const ushort* src = (tile ? xlp : xhp) + (size_t)(row0+sr)*512 + k0 + sg*8;
            char* dst = (tile ? xsl : xsh) + sr*LPITCH + sg*16;
            *reinterpret_cast<uint4*>(dst) = *reinterpret_cast<const uint4*>(src);
        }
#pragma unroll
        for (int u = 0; u < 8; ++u) {
            int i2 = tid + 256*u;
            int tile = i2 >> 10, t2 = i2 & 1023;
            int c = t2 >> 2, sg = t2 & 3;
            const ushort* src = (tile ? Bl : Bh) + (size_t)(col0+c)*512 + k0 + sg*8;
            char* dst = (tile ? wsl : wsh) + c*LPITCH + sg*16;
            *reinterpret_cast<uint4*>(dst) = *reinterpret_cast<const uint4*>(src);
        }
        __syncthreads();
        short8v ah[4], al[4], bh_[4], bl_[4];
#pragma unroll
        for (int mt = 0; mt < 4; ++mt) {
            ah[mt] = *reinterpret_cast<const short8v*>(xsh + (mt*16+lr)*LPITCH + g*16);
            al[mt] = *reinterpret_cast<const short8v*>(xsl + (mt*16+lr)*LPITCH + g*16);
        }
#pragma unroll
        for (int nt = 0; nt < 4; ++nt) {
            bh_[nt] = *reinterpret_cast<const short8v*>(wsh + (w*64+nt*16+lr)*LPITCH + g*16);
            bl_[nt] = *reinterpret_cast<const short8v*>(wsl + (w*64+nt*16+lr)*LPITCH + g*16);
        }
#pragma unroll
        for (int mt = 0; mt < 4; ++mt)
#pragma unroll
            for (int nt = 0; nt < 4; ++nt) {
                acc[mt][nt] = __builtin_amdgcn_mfma_f32_16x16x32_bf16(ah[mt], bh_[nt], acc[mt][nt], 0, 0, 0);
                acc[mt][nt] = __builtin_amdgcn_mfma_f32_16x16x32_bf16(ah[mt], bl_[nt], acc[mt][nt], 0, 0, 0);
                acc[mt][nt] = __builtin_amdgcn_mfma_f32_16x16x32_bf16(al[mt], bh_[nt], acc[mt][nt], 0, 0, 0);
            }
    }

    const int b = row0 / NSEQ;
    const int rem0 = row0 - b*NSEQ;
    if (mid < 2) {
        ushort* dst = (mid==0) ? qa : ka;
        const int sgn = (lr >= 8);
#pragma unroll
        for (int nt = 0; nt < 4; ++nt) {
            int cbase = col0 + w*64 + nt*16;
            int pc = cbase >> 4;
            float a_i = ang[pc], a_j = ang[32 + pc];
            int c = cbase + lr;
            int h = c & 7, v = c >> 3;
            ushort* colbase = dst + ((size_t)(b*NHH + h)*NSEQ)*DPH + v;
#pragma unroll
            for (int mt = 0; mt < 4; ++mt)
#pragma unroll
                for (int r = 0; r < 4; ++r) {
                    int rowrem = rem0 + mt*16 + 4*g + r;
                    int i = rowrem / WW, j = rowrem - (rowrem/WW)*WW;
                    float th = (float)i*a_i + (float)j*a_j;
                    float sn, cn; __sincosf(th, &sn, &cn);
                    float own = acc[mt][nt][r];
                    float oth = __shfl_xor(own, 8);
                    float rot = sgn ? (oth*sn + own*cn) : (own*cn - oth*sn);
                    colbase[(size_t)rowrem*DPH] = f2bf(rot);
                }
        }
    } else {
#pragma unroll
        for (int nt = 0; nt < 4; ++nt) {
            int c = col0 + w*64 + nt*16 + lr;
            int h = c & 7, v = c >> 3;
            ushort* colbase = vT + ((size_t)((b*NHH + h)*DPH + v))*NSEQ + rem0;
#pragma unroll
            for (int mt = 0; mt < 4; ++mt)
#pragma unroll
                for (int r = 0; r < 4; ++r)
                    colbase[mt*16 + 4*g + r] = f2bf(acc[mt][nt][r]);
        }
    }
}

// ---------------------------------------------------------------------------
// Output projection GEMM: A = O_att bf16 [pos][e] (single), B = Bo split.
// ---------------------------------------------------------------------------
__global__ __launch_bounds__(256) void k_gemm_o(
    const ushort* __restrict__ Oa, const ushort* __restrict__ Boh,
    const ushort* __restrict__ Bol, float* __restrict__ out)
{
    __shared__ char xs[64*LPITCH];
    __shared__ char wsh[256*LPITCH], wsl[256*LPITCH];
    const int tid = threadIdx.x;
    const int w = tid>>6, l = tid&63, g = l>>4, lr = l&15;
    const int row0 = (blockIdx.x >> 1)*64;
    const int col0 = (blockIdx.x & 1)*256;

    f32x4 acc[4][4];
#pragma unroll
    for (int mt=0;mt<4;++mt)
#pragma unroll
        for (int nt=0;nt<4;++nt) acc[mt][nt] = (f32x4){0.f,0.f,0.f,0.f};

#pragma unroll 1
    for (int kc = 0; kc < 16; ++kc) {
        const int k0 = kc*32;
        __syncthreads();
        {
            int sr = tid >> 2, sg = tid & 3;
            *reinterpret_cast<uint4*>(xs + sr*LPITCH + sg*16) =
                *reinterpret_cast<const uint4*>(Oa + (size_t)(row0+sr)*512 + k0 + sg*8);
        }
#pragma unroll
        for (int u = 0; u < 8; ++u) {
            int i2 = tid + 256*u;
            int tile = i2 >> 10, t2 = i2 & 1023;
            int c = t2 >> 2, sg = t2 & 3;
            const ushort* src = (tile ? Bol : Boh) + (size_t)(col0+c)*512 + k0 + sg*8;
            char* dst = (tile ? wsl : wsh) + c*LPITCH + sg*16;
            *reinterpret_cast<uint4*>(dst) = *reinterpret_cast<const uint4*>(src);
        }
        __syncthreads();
        short8v a[4], bh_[4], bl_[4];
#pragma unroll
        for (int mt = 0; mt < 4; ++mt)
            a[mt] = *reinterpret_cast<const short8v*>(xs + (mt*16+lr)*LPITCH + g*16);
#pragma unroll
        for (int nt = 0; nt < 4; ++nt) {
            bh_[nt] = *reinterpret_cast<const short8v*>(wsh + (w*64+nt*16+lr)*LPITCH + g*16);
            bl_[nt] = *reinterpret_cast<const short8v*>(wsl + (w*64+nt*16+lr)*LPITCH + g*16);
        }
#pragma unroll
        for (int mt = 0; mt < 4; ++mt)
#pragma unroll
            for (int nt = 0; nt < 4; ++nt) {
                acc[mt][nt] = __builtin_amdgcn_mfma_f32_16x16x32_bf16(a[mt], bh_[nt], acc[mt][nt], 0, 0, 0);
                acc[mt][nt] = __builtin_amdgcn_mfma_f32_16x16x32_bf16(a[mt], bl_[nt], acc[mt][nt], 0, 0, 0);
            }
    }

#pragma unroll
    for (int mt=0;mt<4;++mt)
#pragma unroll
        for (int r=0;r<4;++r) {
            float* rowp = out + (size_t)(row0 + mt*16 + 4*g + r)*DD + col0 + w*64;
#pragma unroll
            for (int nt=0;nt<4;++nt)
                rowp[nt*16 + lr] = acc[mt][nt][r];
        }
}

// ---------------------------------------------------------------------------
// Flash attention, bf16 MFMA, split-KV (2 splits of 18 chunks).
// SWAPPED QK^T (D = S^T): each lane owns one q-row (q = lr), 16 kv scores in
// regs -> in-lane softmax reductions (2 shfl_xor instead of 8 per row),
// packed b64 P writes. Writes unnormalized partial O (bf16) + per-row (m,l).
// ---------------------------------------------------------------------------
#define CK 64
#define KP 72              // LDS pitch (bf16 elems) -> 144 B rows
__global__ __launch_bounds__(256) void k_attn_mfma(
    const ushort* __restrict__ qb, const ushort* __restrict__ kb,
    const ushort* __restrict__ vb, ushort* __restrict__ Op,
    float2* __restrict__ mlp)
{
    __shared__ ushort ksm[CK][KP];
    __shared__ ushort vsm[CK][KP];
    __shared__ ushort psm[4][16][KP];    // per-wave P [q][kv]
    const int tid = threadIdx.x;
    const int w = tid >> 6, l = tid & 63;
    const int g = l >> 4, lr = l & 15;
    const int sp  = blockIdx.x / 576;
    const int rest = blockIdx.x - sp*576;
    const int bh = rest / 36;
    const int qc = rest - bh*36;
    const int row0 = qc * 64;
    const ushort* kbase = kb + (size_t)bh*NSEQ*DPH;
    const ushort* vbase = vb + (size_t)bh*DPH*NSEQ;

    // Q fragment (B-operand of swapped QK): col=lr -> q row, k=8g+j -> d
    const ushort* qptr = qb + ((size_t)bh*NSEQ + row0 + 16*w + lr)*DPH + g*8;
    const short8v qB0 = *reinterpret_cast<const short8v*>(qptr);
    const short8v qB1 = *reinterpret_cast<const short8v*>(qptr + 32);

    float m_ln = -INFINITY, l_ln = 0.f;   // per-lane state for q = lr
    f32x4 o[4];
#pragma unroll
    for (int vt = 0; vt < 4; ++vt) o[vt] = (f32x4){0.f,0.f,0.f,0.f};

    for (int t = sp*18; t < sp*18 + 18; ++t) {
        __syncthreads();
#pragma unroll
        for (int i = 0; i < 2; ++i) {
            int tau = tid + 256*i;
            int row = tau >> 3, cg = tau & 7;
            *reinterpret_cast<uint4*>(&ksm[row][cg*8]) =
                *reinterpret_cast<const uint4*>(kbase + ((size_t)(t*CK + row))*DPH + cg*8);
            *reinterpret_cast<uint4*>(&vsm[row][cg*8]) =
                *reinterpret_cast<const uint4*>(vbase + (size_t)row*NSEQ + t*CK + cg*8);
        }
        __syncthreads();

        // ---- S^T = K Q^T : sc[tile][r] = S[kv=16t+4g+r][q=lr]
        f32x4 sc[4];
#pragma unroll
        for (int tile = 0; tile < 4; ++tile) {
            short8v k0 = *reinterpret_cast<const short8v*>(&ksm[tile*16 + lr][g*8]);
            short8v k1 = *reinterpret_cast<const short8v*>(&ksm[tile*16 + lr][32 + g*8]);
            f32x4 a2 = (f32x4){0.f,0.f,0.f,0.f};
            a2 = __builtin_amdgcn_mfma_f32_16x16x32_bf16(k0, qB0, a2, 0, 0, 0);
            a2 = __builtin_amdgcn_mfma_f32_16x16x32_bf16(k1, qB1, a2, 0, 0, 0);
            sc[tile] = a2;
        }

        // ---- online softmax: in-lane over 16 values, then reduce over g
        float cm = sc[0][0];
#pragma unroll
        for (int tile = 0; tile < 4; ++tile)
#pragma unroll
            for (int r = 0; r < 4; ++r)
                cm = fmaxf(cm, sc[tile][r]);
        cm = fmaxf(cm, __shfl_xor(cm, 16));
        cm = fmaxf(cm, __shfl_xor(cm, 32));
        float mn = fmaxf(m_ln, cm);
        float f = __expf(m_ln - mn);
        m_ln = mn;
        float rs = 0.f;
#pragma unroll
        for (int tile = 0; tile < 4; ++tile)
#pragma unroll
            for (int r = 0; r < 4; ++r) {
                float p = __expf(sc[tile][r] - mn);
                sc[tile][r] = p;
                rs += p;
            }
        rs += __shfl_xor(rs, 16);
        rs += __shfl_xor(rs, 32);
        l_ln = l_ln*f + rs;

        // ---- P pack: 4 consecutive kv per tile -> b64 writes psm[q=lr][16t+4g]
#pragma unroll
        for (int tile = 0; tile < 4; ++tile) {
            uint2 pk;
            pk.x = pack2bf(sc[tile][0], sc[tile][1]);
            pk.y = pack2bf(sc[tile][2], sc[tile][3]);
            *reinterpret_cast<uint2*>(&psm[w][lr][16*tile + 4*g]) = pk;
        }

        // ---- O rescale: row 4g+r needs f of q=4g+r (lane lr'=4g+r in group)
        float f4[4];
#pragma unroll
        for (int r = 0; r < 4; ++r)
            f4[r] = __shfl(f, 4*g + r, 16);
#pragma unroll
        for (int vt = 0; vt < 4; ++vt)
#pragma unroll
            for (int r = 0; r < 4; ++r)
                o[vt][r] *= f4[r];

        // ---- O += P V
#pragma unroll
        for (int half = 0; half < 2; ++half) {
            short8v pA = *reinterpret_cast<const short8v*>(&psm[w][lr][32*half + g*8]);
#pragma unroll
            for (int vt = 0; vt < 4; ++vt) {
                short8v vf = *reinterpret_cast<const short8v*>(&vsm[vt*16 + lr][32*half + g*8]);
                o[vt] = __builtin_amdgcn_mfma_f32_16x16x32_bf16(pA, vf, o[vt], 0, 0, 0);
            }
        }
    }

    // ---- store unnormalized partial O (bf16) + (m,l) per row
    ushort* obase = Op + ((size_t)sp*NROWS + (size_t)bh*NSEQ + row0 + 16*w)*64;
#pragma unroll
    for (int vt = 0; vt < 4; ++vt)
#pragma unroll
        for (int r = 0; r < 4; ++r)
            obase[(4*g + r)*64 + vt*16 + lr] = f2bf(o[vt][r]);
    if (g == 0)
        mlp[sp*NROWS + bh*NSEQ + row0 + 16*w + lr] = make_float2(m_ln, l_ln);
}

// ---------------------------------------------------------------------------
// Combine the 2 KV-splits: O = (O0*e^{m0-M} + O1*e^{m1-M}) / (l0*e^{m0-M}+l1*e^{m1-M})
// Writes bf16 Oa[pos][e = h*64+v] for the output GEMM.
// ---------------------------------------------------------------------------
__global__ __launch_bounds__(256) void k_combine(
    const ushort* __restrict__ Op, const float2* __restrict__ mlp,
    ushort* __restrict__ Oa)
{
    const int tid = threadIdx.x;
    const int row = blockIdx.x*32 + (tid >> 3);
    const int c8 = (tid & 7)*8;
    float2 a = mlp[row], b = mlp[NROWS + row];
    float M = fmaxf(a.x, b.x);
    float w0 = __expf(a.x - M), w1 = __expf(b.x - M);
    float inv = 1.f / (a.y*w0 + b.y*w1);
    const ushort* p0 = Op + (size_t)row*64 + c8;
    const ushort* p1 = p0 + (size_t)NROWS*64;
    uint4 u0 = *reinterpret_cast<const uint4*>(p0);
    uint4 u1 = *reinterpret_cast<const uint4*>(p1);
    const ushort* s0 = reinterpret_cast<const ushort*>(&u0);
    const ushort* s1 = reinterpret_cast<const ushort*>(&u1);
    ushort res[8];
#pragma unroll
    for (int i = 0; i < 8; ++i)
        res[i] = f2bf((bf2f(s0[i])*w0 + bf2f(s1[i])*w1) * inv);
    int bh = row / NSEQ, n = row - bh*NSEQ;
    int b_ = bh >> 3, h_ = bh & 7;
    ushort* dst = Oa + ((size_t)(b_*NSEQ + n))*DD + h_*64 + c8;
    *reinterpret_cast<uint4*>(dst) = *reinterpret_cast<const uint4*>(res);
}

// ---------------------------------------------------------------------------
extern "C" void kernel_launch(void* const* d_in, const int* in_sizes, int n_in,
                              void* d_out, int out_size, void* d_ws, size_t ws_size,
                              hipStream_t stream) {
    const float* x   = (const float*)d_in[0];
    const float* wq  = (const float*)d_in[1];
    const float* wk  = (const float*)d_in[2];
    const float* wv  = (const float*)d_in[3];
    const float* wo  = (const float*)d_in[4];
    const float* ang = (const float*)d_in[5];
    float* out = (float*)d_out;

    ushort* xh  = (ushort*)d_ws;         // [4608][512]; aliased as Op[0..1] after qkv
    ushort* xl  = xh + NXE;
    ushort* Bqh = xl + NXE;              // 8 x [512][512]
    ushort* Bql = Bqh + WSZ;
    ushort* Bkh = Bql + WSZ;
    ushort* Bkl = Bkh + WSZ;
    ushort* Bvh = Bkl + WSZ;
    ushort* Bvl = Bvh + WSZ;
    ushort* Boh = Bvl + WSZ;
    ushort* Bol = Boh + WSZ;
    ushort* qa  = Bol + WSZ;             // [16][2304][64]
    ushort* ka  = qa + NXE;
    ushort* vT  = ka + NXE;
    ushort* Oa  = vT + NXE;              // [4608][512] bf16
    ushort* Op  = xh;                    // [2][36864][64] partial O (aliases x splits)
    float2* mlp = (float2*)Bqh;          // [2][36864] (aliases dead Bq panels)

    k_prep<<<(NXE + 4*WSZ)/256, 256, 0, stream>>>(x, wq, wk, wv, wo,
        xh, xl, Bqh, Bql, Bkh, Bkl, Bvh, Bvl, Boh, Bol);
    k_gemm_qkv<<<432, 256, 0, stream>>>(xh, xl, Bqh, Bql, Bkh, Bkl, Bvh, Bvl,
        ang, qa, ka, vT);
    k_attn_mfma<<<1152, 256, 0, stream>>>(qa, ka, vT, Op, mlp);
    k_combine<<<NROWS/32, 256, 0, stream>>>(Op, mlp, Oa);
    k_gemm_o<<<144, 256, 0, stream>>>(Oa, Boh, Bol, out);
}

// Round 11
// 198.822 us; speedup vs baseline: 4.7830x; 1.0073x over previous
//
#include <hip/hip_runtime.h>
#include <hip/hip_bf16.h>
#include <math.h>

// Problem constants (fixed by setup_inputs)
#define BB   2
#define WW   48
#define DD   512
#define DPH  64
#define NHH  8
#define NSEQ 2304
#define NPOS (BB*NSEQ)      // 4608
#define NXE  (NPOS*DD)      // 2359296
#define WSZ  (DD*DD)        // 262144
#define NROWS (BB*NHH*NSEQ) // 36864 attention rows

typedef __attribute__((ext_vector_type(8))) short short8v;  // 8 bf16
typedef __attribute__((ext_vector_type(4))) float f32x4;

__device__ __forceinline__ ushort f2bf(float f) {
    union { __hip_bfloat16 h; ushort u; } cv;
    cv.h = __float2bfloat16(f);
    return cv.u;
}
__device__ __forceinline__ float bf2f(ushort u) {
    return __uint_as_float(((uint)u) << 16);
}
__device__ __forceinline__ uint pack2bf(float lo, float hi) {
    return (uint)f2bf(lo) | ((uint)f2bf(hi) << 16);
}
__device__ __forceinline__ float fexp2(float x) {
#if __has_builtin(__builtin_amdgcn_exp2f)
    return __builtin_amdgcn_exp2f(x);
#else
    return exp2f(x);
#endif
}
#define QSCL (0.125f * 1.44269504088896f)   // 1/sqrt(64) * log2(e)

// ---------------------------------------------------------------------------
// Prep: split-precision bf16 (hi + lo residual) for x and all weight panels.
// Bq carries QSCL so QK^T scores come out in log2 domain (exp2 softmax).
// ---------------------------------------------------------------------------
__global__ __launch_bounds__(256) void k_prep(
    const float* __restrict__ x,  const float* __restrict__ wq,
    const float* __restrict__ wk, const float* __restrict__ wv,
    const float* __restrict__ wo,
    ushort* __restrict__ xh, ushort* __restrict__ xl,
    ushort* __restrict__ Bqh, ushort* __restrict__ Bql,
    ushort* __restrict__ Bkh, ushort* __restrict__ Bkl,
    ushort* __restrict__ Bvh, ushort* __restrict__ Bvl,
    ushort* __restrict__ Boh, ushort* __restrict__ Bol)
{
    int idx = blockIdx.x*256 + threadIdx.x;      // grid covers NXE + 4*WSZ exactly
    float s;
    ushort *ph, *pl; int o;
    if (idx < NXE) {
        s = x[idx]; ph = xh; pl = xl; o = idx;
    } else {
        int t = idx - NXE;
        int sel = t >> 18;
        o = t & (WSZ-1);
        int c = o >> 9, k = o & 511;
        if (sel == 0)      { s = wq[k*512 + c] * QSCL;   ph = Bqh; pl = Bql; }
        else if (sel == 1) { s = wk[k*512 + c];          ph = Bkh; pl = Bkl; }
        else if (sel == 2) { s = wv[k*512 + c];          ph = Bvh; pl = Bvl; }
        else               { s = wo[c*512 + ((k&63)<<3) + (k>>6)]; ph = Boh; pl = Bol; }
    }
    ushort hi = f2bf(s);
    ph[o] = hi;
    pl[o] = f2bf(s - bf2f(hi));
}

// ---------------------------------------------------------------------------
// QKV GEMM, split-precision (3 MFMA products), fused RoPE epilogue.
// 64x128 tiles, 30 KB LDS -> 5 blocks/CU, grid 864 (3.4/CU).
// ---------------------------------------------------------------------------
#define LPITCH 80
__global__ __launch_bounds__(256) void k_gemm_qkv(
    const ushort* __restrict__ xhp, const ushort* __restrict__ xlp,
    const ushort* __restrict__ Bqh, const ushort* __restrict__ Bql,
    const ushort* __restrict__ Bkh, const ushort* __restrict__ Bkl,
    const ushort* __restrict__ Bvh, const ushort* __restrict__ Bvl,
    const float* __restrict__ ang,
    ushort* __restrict__ qa, ushort* __restrict__ ka, ushort* __restrict__ vT)
{
    __shared__ char xsh[64*LPITCH], xsl[64*LPITCH];
    __shared__ char wsh[128*LPITCH], wsl[128*LPITCH];
    const int tid = threadIdx.x;
    const int w = tid>>6, l = tid&63, g = l>>4, lr = l&15;
    const int mid = blockIdx.x / 288;
    const int rmb = blockIdx.x - mid*288;
    const int rowblk = rmb >> 2, colblk = rmb & 3;
    const int row0 = rowblk*64, col0 = colblk*128;
    const ushort* Bh; const ushort* Bl;
    if (mid==0)      { Bh = Bqh; Bl = Bql; }
    else if (mid==1) { Bh = Bkh; Bl = Bkl; }
    else             { Bh = Bvh; Bl = Bvl; }

    f32x4 acc[4][2];
#pragma unroll
    for (int mt=0;mt<4;++mt)
#pragma unroll
        for (int nt=0;nt<2;++nt) acc[mt][nt] = (f32x4){0.f,0.f,0.f,0.f};

#pragma unroll 1
    for (int kc = 0; kc < 16; ++kc) {
        const int k0 = kc*32;
        __syncthreads();
        // stage A tiles (hi, lo): 512 uint4, 2 per thread
#pragma unroll
        for (int u = 0; u < 2; ++u) {
            int i2 = tid + 256*u;
            int tile = i2 >> 8, t2 = i2 & 255;
            int sr = t2 >> 2, sg = t2 & 3;
            const ushort* src = (tile ? xlp : xhp) + (size_t)(row0+sr)*512 + k0 + sg*8;
            char* dst = (tile ? xsl : xsh) + sr*LPITCH + sg*16;
            *reinterpret_cast<uint4*>(dst) = *reinterpret_cast<const uint4*>(src);
        }
        // stage B tiles (hi, lo): 1024 uint4, 4 per thread
#pragma unroll
        for (int u = 0; u < 4; ++u) {
            int i2 = tid + 256*u;
            int tile = i2 >> 9, t2 = i2 & 511;
            int c = t2 >> 2, sg = t2 & 3;
            const ushort* src = (tile ? Bl : Bh) + (size_t)(col0+c)*512 + k0 + sg*8;
            char* dst = (tile ? wsl : wsh) + c*LPITCH + sg*16;
            *reinterpret_cast<uint4*>(dst) = *reinterpret_cast<const uint4*>(src);
        }
        __syncthreads();
        short8v ah[4], al[4], bh_[2], bl_[2];
#pragma unroll
        for (int mt = 0; mt < 4; ++mt) {
            ah[mt] = *reinterpret_cast<const short8v*>(xsh + (mt*16+lr)*LPITCH + g*16);
            al[mt] = *reinterpret_cast<const short8v*>(xsl + (mt*16+lr)*LPITCH + g*16);
        }
#pragma unroll
        for (int nt = 0; nt < 2; ++nt) {
            bh_[nt] = *reinterpret_cast<const short8v*>(wsh + (w*32+nt*16+lr)*LPITCH + g*16);
            bl_[nt] = *reinterpret_cast<const short8v*>(wsl + (w*32+nt*16+lr)*LPITCH + g*16);
        }
#pragma unroll
        for (int mt = 0; mt < 4; ++mt)
#pragma unroll
            for (int nt = 0; nt < 2; ++nt) {
                acc[mt][nt] = __builtin_amdgcn_mfma_f32_16x16x32_bf16(ah[mt], bh_[nt], acc[mt][nt], 0, 0, 0);
                acc[mt][nt] = __builtin_amdgcn_mfma_f32_16x16x32_bf16(ah[mt], bl_[nt], acc[mt][nt], 0, 0, 0);
                acc[mt][nt] = __builtin_amdgcn_mfma_f32_16x16x32_bf16(al[mt], bh_[nt], acc[mt][nt], 0, 0, 0);
            }
    }

    const int b = row0 / NSEQ;
    const int rem0 = row0 - b*NSEQ;
    if (mid < 2) {
        ushort* dst = (mid==0) ? qa : ka;
        const int sgn = (lr >= 8);
#pragma unroll
        for (int nt = 0; nt < 2; ++nt) {
            int cbase = col0 + w*32 + nt*16;
            int pc = cbase >> 4;
            float a_i = ang[pc], a_j = ang[32 + pc];
            int c = cbase + lr;
            int h = c & 7, v = c >> 3;
            ushort* colbase = dst + ((size_t)(b*NHH + h)*NSEQ)*DPH + v;
#pragma unroll
            for (int mt = 0; mt < 4; ++mt)
#pragma unroll
                for (int r = 0; r < 4; ++r) {
                    int rowrem = rem0 + mt*16 + 4*g + r;
                    int i = rowrem / WW, j = rowrem - (rowrem/WW)*WW;
                    float th = (float)i*a_i + (float)j*a_j;
                    float sn, cn; __sincosf(th, &sn, &cn);
                    float own = acc[mt][nt][r];
                    float oth = __shfl_xor(own, 8);
                    float rot = sgn ? (oth*sn + own*cn) : (own*cn - oth*sn);
                    colbase[(size_t)rowrem*DPH] = f2bf(rot);
                }
        }
    } else {
#pragma unroll
        for (int nt = 0; nt < 2; ++nt) {
            int c = col0 + w*32 + nt*16 + lr;
            int h = c & 7, v = c >> 3;
            ushort* colbase = vT + ((size_t)((b*NHH + h)*DPH + v))*NSEQ + rem0;
#pragma unroll
            for (int mt = 0; mt < 4; ++mt)
#pragma unroll
                for (int r = 0; r < 4; ++r)
                    colbase[mt*16 + 4*g + r] = f2bf(acc[mt][nt][r]);
        }
    }
}

// ---------------------------------------------------------------------------
// Output projection GEMM: A = O_att bf16 [pos][e] (single), B = Bo split.
// 64x128 tiles, grid 288.
// ---------------------------------------------------------------------------
__global__ __launch_bounds__(256) void k_gemm_o(
    const ushort* __restrict__ Oa, const ushort* __restrict__ Boh,
    const ushort* __restrict__ Bol, float* __restrict__ out)
{
    __shared__ char xs[64*LPITCH];
    __shared__ char wsh[128*LPITCH], wsl[128*LPITCH];
    const int tid = threadIdx.x;
    const int w = tid>>6, l = tid&63, g = l>>4, lr = l&15;
    const int row0 = (blockIdx.x >> 2)*64;
    const int col0 = (blockIdx.x & 3)*128;

    f32x4 acc[4][2];
#pragma unroll
    for (int mt=0;mt<4;++mt)
#pragma unroll
        for (int nt=0;nt<2;++nt) acc[mt][nt] = (f32x4){0.f,0.f,0.f,0.f};

#pragma unroll 1
    for (int kc = 0; kc < 16; ++kc) {
        const int k0 = kc*32;
        __syncthreads();
        {   // stage A tile: 256 uint4, 1 per thread
            int sr = tid >> 2, sg = tid & 3;
            *reinterpret_cast<uint4*>(xs + sr*LPITCH + sg*16) =
                *reinterpret_cast<const uint4*>(Oa + (size_t)(row0+sr)*512 + k0 + sg*8);
        }
#pragma unroll
        for (int u = 0; u < 4; ++u) {   // stage B tiles (hi, lo): 4 per thread
            int i2 = tid + 256*u;
            int tile = i2 >> 9, t2 = i2 & 511;
            int c = t2 >> 2, sg = t2 & 3;
            const ushort* src = (tile ? Bol : Boh) + (size_t)(col0+c)*512 + k0 + sg*8;
            char* dst = (tile ? wsl : wsh) + c*LPITCH + sg*16;
            *reinterpret_cast<uint4*>(dst) = *reinterpret_cast<const uint4*>(src);
        }
        __syncthreads();
        short8v a[4], bh_[2], bl_[2];
#pragma unroll
        for (int mt = 0; mt < 4; ++mt)
            a[mt] = *reinterpret_cast<const short8v*>(xs + (mt*16+lr)*LPITCH + g*16);
#pragma unroll
        for (int nt = 0; nt < 2; ++nt) {
            bh_[nt] = *reinterpret_cast<const short8v*>(wsh + (w*32+nt*16+lr)*LPITCH + g*16);
            bl_[nt] = *reinterpret_cast<const short8v*>(wsl + (w*32+nt*16+lr)*LPITCH + g*16);
        }
#pragma unroll
        for (int mt = 0; mt < 4; ++mt)
#pragma unroll
            for (int nt = 0; nt < 2; ++nt) {
                acc[mt][nt] = __builtin_amdgcn_mfma_f32_16x16x32_bf16(a[mt], bh_[nt], acc[mt][nt], 0, 0, 0);
                acc[mt][nt] = __builtin_amdgcn_mfma_f32_16x16x32_bf16(a[mt], bl_[nt], acc[mt][nt], 0, 0, 0);
            }
    }

#pragma unroll
    for (int mt=0;mt<4;++mt)
#pragma unroll
        for (int r=0;r<4;++r) {
            float* rowp = out + (size_t)(row0 + mt*16 + 4*g + r)*DD + col0 + w*32;
#pragma unroll
            for (int nt=0;nt<2;++nt)
                rowp[nt*16 + lr] = acc[mt][nt][r];
        }
}

// ---------------------------------------------------------------------------
// Flash attention, bf16 MFMA, split-KV (2 splits of 18 chunks).
// Swapped QK^T (D = S^T): lane owns one q-row, in-lane softmax (exp2 domain).
// ---------------------------------------------------------------------------
#define CK 64
#define KP 72              // LDS pitch (bf16 elems) -> 144 B rows
__global__ __launch_bounds__(256) void k_attn_mfma(
    const ushort* __restrict__ qb, const ushort* __restrict__ kb,
    const ushort* __restrict__ vb, ushort* __restrict__ Op,
    float2* __restrict__ mlp)
{
    __shared__ ushort ksm[CK][KP];
    __shared__ ushort vsm[CK][KP];
    __shared__ ushort psm[4][16][KP];    // per-wave P [q][kv]
    const int tid = threadIdx.x;
    const int w = tid >> 6, l = tid & 63;
    const int g = l >> 4, lr = l & 15;
    const int sp  = blockIdx.x / 576;
    const int rest = blockIdx.x - sp*576;
    const int bh = rest / 36;
    const int qc = rest - bh*36;
    const int row0 = qc * 64;
    const ushort* kbase = kb + (size_t)bh*NSEQ*DPH;
    const ushort* vbase = vb + (size_t)bh*DPH*NSEQ;

    // Q fragment (B-operand of swapped QK): col=lr -> q row, k=8g+j -> d
    const ushort* qptr = qb + ((size_t)bh*NSEQ + row0 + 16*w + lr)*DPH + g*8;
    const short8v qB0 = *reinterpret_cast<const short8v*>(qptr);
    const short8v qB1 = *reinterpret_cast<const short8v*>(qptr + 32);

    float m_ln = -INFINITY, l_ln = 0.f;   // per-lane state for q = lr (log2 domain)
    f32x4 o[4];
#pragma unroll
    for (int vt = 0; vt < 4; ++vt) o[vt] = (f32x4){0.f,0.f,0.f,0.f};

    for (int t = sp*18; t < sp*18 + 18; ++t) {
        __syncthreads();
#pragma unroll
        for (int i = 0; i < 2; ++i) {
            int tau = tid + 256*i;
            int row = tau >> 3, cg = tau & 7;
            *reinterpret_cast<uint4*>(&ksm[row][cg*8]) =
                *reinterpret_cast<const uint4*>(kbase + ((size_t)(t*CK + row))*DPH + cg*8);
            *reinterpret_cast<uint4*>(&vsm[row][cg*8]) =
                *reinterpret_cast<const uint4*>(vbase + (size_t)row*NSEQ + t*CK + cg*8);
        }
        __syncthreads();

        // ---- S^T = K Q^T : sc[tile][r] = S[kv=16t+4g+r][q=lr] (log2 units)
        f32x4 sc[4];
#pragma unroll
        for (int tile = 0; tile < 4; ++tile) {
            short8v k0 = *reinterpret_cast<const short8v*>(&ksm[tile*16 + lr][g*8]);
            short8v k1 = *reinterpret_cast<const short8v*>(&ksm[tile*16 + lr][32 + g*8]);
            f32x4 a2 = (f32x4){0.f,0.f,0.f,0.f};
            a2 = __builtin_amdgcn_mfma_f32_16x16x32_bf16(k0, qB0, a2, 0, 0, 0);
            a2 = __builtin_amdgcn_mfma_f32_16x16x32_bf16(k1, qB1, a2, 0, 0, 0);
            sc[tile] = a2;
        }

        // ---- online softmax (exp2): in-lane over 16 values, then reduce over g
        float cm = sc[0][0];
#pragma unroll
        for (int tile = 0; tile < 4; ++tile)
#pragma unroll
            for (int r = 0; r < 4; ++r)
                cm = fmaxf(cm, sc[tile][r]);
        cm = fmaxf(cm, __shfl_xor(cm, 16));
        cm = fmaxf(cm, __shfl_xor(cm, 32));
        float mn = fmaxf(m_ln, cm);
        float f = fexp2(m_ln - mn);
        m_ln = mn;
        float rs = 0.f;
#pragma unroll
        for (int tile = 0; tile < 4; ++tile)
#pragma unroll
            for (int r = 0; r < 4; ++r) {
                float p = fexp2(sc[tile][r] - mn);
                sc[tile][r] = p;
                rs += p;
            }
        rs += __shfl_xor(rs, 16);
        rs += __shfl_xor(rs, 32);
        l_ln = l_ln*f + rs;

        // ---- P pack: 4 consecutive kv per tile -> b64 writes psm[q=lr][16t+4g]
#pragma unroll
        for (int tile = 0; tile < 4; ++tile) {
            uint2 pk;
            pk.x = pack2bf(sc[tile][0], sc[tile][1]);
            pk.y = pack2bf(sc[tile][2], sc[tile][3]);
            *reinterpret_cast<uint2*>(&psm[w][lr][16*tile + 4*g]) = pk;
        }

        // ---- O rescale: row 4g+r needs f of q=4g+r (lane lr'=4g+r in group)
        float f4[4];
#pragma unroll
        for (int r = 0; r < 4; ++r)
            f4[r] = __shfl(f, 4*g + r, 16);
#pragma unroll
        for (int vt = 0; vt < 4; ++vt)
#pragma unroll
            for (int r = 0; r < 4; ++r)
                o[vt][r] *= f4[r];

        // ---- O += P V
#pragma unroll
        for (int half = 0; half < 2; ++half) {
            short8v pA = *reinterpret_cast<const short8v*>(&psm[w][lr][32*half + g*8]);
#pragma unroll
            for (int vt = 0; vt < 4; ++vt) {
                short8v vf = *reinterpret_cast<const short8v*>(&vsm[vt*16 + lr][32*half + g*8]);
                o[vt] = __builtin_amdgcn_mfma_f32_16x16x32_bf16(pA, vf, o[vt], 0, 0, 0);
            }
        }
    }

    // ---- store unnormalized partial O (bf16) + (m,l) per row
    ushort* obase = Op + ((size_t)sp*NROWS + (size_t)bh*NSEQ + row0 + 16*w)*64;
#pragma unroll
    for (int vt = 0; vt < 4; ++vt)
#pragma unroll
        for (int r = 0; r < 4; ++r)
            obase[(4*g + r)*64 + vt*16 + lr] = f2bf(o[vt][r]);
    if (g == 0)
        mlp[sp*NROWS + bh*NSEQ + row0 + 16*w + lr] = make_float2(m_ln, l_ln);
}

// ---------------------------------------------------------------------------
// Combine the 2 KV-splits (log2-domain m): O = sum O_i*2^{m_i-M} / sum l_i*2^{m_i-M}
// Writes bf16 Oa[pos][e = h*64+v] for the output GEMM.
// ---------------------------------------------------------------------------
__global__ __launch_bounds__(256) void k_combine(
    const ushort* __restrict__ Op, const float2* __restrict__ mlp,
    ushort* __restrict__ Oa)
{
    const int tid = threadIdx.x;
    const int row = blockIdx.x*32 + (tid >> 3);
    const int c8 = (tid & 7)*8;
    float2 a = mlp[row], b = mlp[NROWS + row];
    float M = fmaxf(a.x, b.x);
    float w0 = fexp2(a.x - M), w1 = fexp2(b.x - M);
    float inv = 1.f / (a.y*w0 + b.y*w1);
    const ushort* p0 = Op + (size_t)row*64 + c8;
    const ushort* p1 = p0 + (size_t)NROWS*64;
    uint4 u0 = *reinterpret_cast<const uint4*>(p0);
    uint4 u1 = *reinterpret_cast<const uint4*>(p1);
    const ushort* s0 = reinterpret_cast<const ushort*>(&u0);
    const ushort* s1 = reinterpret_cast<const ushort*>(&u1);
    ushort res[8];
#pragma unroll
    for (int i = 0; i < 8; ++i)
        res[i] = f2bf((bf2f(s0[i])*w0 + bf2f(s1[i])*w1) * inv);
    int bh = row / NSEQ, n = row - bh*NSEQ;
    int b_ = bh >> 3, h_ = bh & 7;
    ushort* dst = Oa + ((size_t)(b_*NSEQ + n))*DD + h_*64 + c8;
    *reinterpret_cast<uint4*>(dst) = *reinterpret_cast<const uint4*>(res);
}

// ---------------------------------------------------------------------------
extern "C" void kernel_launch(void* const* d_in, const int* in_sizes, int n_in,
                              void* d_out, int out_size, void* d_ws, size_t ws_size,
                              hipStream_t stream) {
    const float* x   = (const float*)d_in[0];
    const float* wq  = (const float*)d_in[1];
    const float* wk  = (const float*)d_in[2];
    const float* wv  = (const float*)d_in[3];
    const float* wo  = (const float*)d_in[4];
    const float* ang = (const float*)d_in[5];
    float* out = (float*)d_out;

    ushort* xh  = (ushort*)d_ws;         // [4608][512]; aliased as Op[0..1] after qkv
    ushort* xl  = xh + NXE;
    ushort* Bqh = xl + NXE;              // 8 x [512][512]
    ushort* Bql = Bqh + WSZ;
    ushort* Bkh = Bql + WSZ;
    ushort* Bkl = Bkh + WSZ;
    ushort* Bvh = Bkl + WSZ;
    ushort* Bvl = Bvh + WSZ;
    ushort* Boh = Bvl + WSZ;
    ushort* Bol = Boh + WSZ;
    ushort* qa  = Bol + WSZ;             // [16][2304][64]
    ushort* ka  = qa + NXE;
    ushort* vT  = ka + NXE;
    ushort* Oa  = vT + NXE;              // [4608][512] bf16
    ushort* Op  = xh;                    // [2][36864][64] partial O (aliases x splits)
    float2* mlp = (float2*)Bqh;          // [2][36864] (aliases dead Bq panels)

    k_prep<<<(NXE + 4*WSZ)/256, 256, 0, stream>>>(x, wq, wk, wv, wo,
        xh, xl, Bqh, Bql, Bkh, Bkl, Bvh, Bvl, Boh, Bol);
    k_gemm_qkv<<<864, 256, 0, stream>>>(xh, xl, Bqh, Bql, Bkh, Bkl, Bvh, Bvl,
        ang, qa, ka, vT);
    k_attn_mfma<<<1152, 256, 0, stream>>>(qa, ka, vT, Op, mlp);
    k_combine<<<NROWS/32, 256, 0, stream>>>(Op, mlp, Oa);
    k_gemm_o<<<288, 256, 0, stream>>>(Oa, Boh, Bol, out);
}

// Round 12
// 192.385 us; speedup vs baseline: 4.9430x; 1.0335x over previous
//
#include <hip/hip_runtime.h>
#include <hip/hip_bf16.h>
#include <math.h>

// Problem constants (fixed by setup_inputs)
#define BB   2
#define WW   48
#define DD   512
#define DPH  64
#define NHH  8
#define NSEQ 2304
#define NPOS (BB*NSEQ)      // 4608
#define NXE  (NPOS*DD)      // 2359296
#define WSZ  (DD*DD)        // 262144
#define NROWS (BB*NHH*NSEQ) // 36864 attention rows

typedef __attribute__((ext_vector_type(8))) short short8v;  // 8 bf16
typedef __attribute__((ext_vector_type(4))) float f32x4;

__device__ __forceinline__ ushort f2bf(float f) {
    union { __hip_bfloat16 h; ushort u; } cv;
    cv.h = __float2bfloat16(f);
    return cv.u;
}
__device__ __forceinline__ float bf2f(ushort u) {
    return __uint_as_float(((uint)u) << 16);
}
__device__ __forceinline__ uint pack2bf(float lo, float hi) {
    return (uint)f2bf(lo) | ((uint)f2bf(hi) << 16);
}
__device__ __forceinline__ float fexp2(float x) {
#if __has_builtin(__builtin_amdgcn_exp2f)
    return __builtin_amdgcn_exp2f(x);
#else
    return exp2f(x);
#endif
}
#define QSCL (0.125f * 1.44269504088896f)   // 1/sqrt(64) * log2(e)

// ---------------------------------------------------------------------------
// Prep: split-precision bf16 (hi + lo residual) for x and all weight panels.
// Column order for Bq/Bk/Bv is e = h*64+v (head-major) -> projections emit
// row-major [pos][e] with per-head contiguous runs. Bo[d][e] as before.
// ---------------------------------------------------------------------------
__global__ __launch_bounds__(256) void k_prep(
    const float* __restrict__ x,  const float* __restrict__ wq,
    const float* __restrict__ wk, const float* __restrict__ wv,
    const float* __restrict__ wo,
    ushort* __restrict__ xh, ushort* __restrict__ xl,
    ushort* __restrict__ Bqh, ushort* __restrict__ Bql,
    ushort* __restrict__ Bkh, ushort* __restrict__ Bkl,
    ushort* __restrict__ Bvh, ushort* __restrict__ Bvl,
    ushort* __restrict__ Boh, ushort* __restrict__ Bol)
{
    int idx = blockIdx.x*256 + threadIdx.x;      // grid covers NXE + 4*WSZ exactly
    float s;
    ushort *ph, *pl; int o;
    if (idx < NXE) {
        s = x[idx]; ph = xh; pl = xl; o = idx;
    } else {
        int t = idx - NXE;
        int sel = t >> 18;
        o = t & (WSZ-1);
        int c = o >> 9, k = o & 511;
        int widx = k*512 + ((c & 63) << 3) + (c >> 6);   // w[d=k][v=c&63][h=c>>6]
        if (sel == 0)      { s = wq[widx] * QSCL; ph = Bqh; pl = Bql; }
        else if (sel == 1) { s = wk[widx];        ph = Bkh; pl = Bkl; }
        else if (sel == 2) { s = wv[widx];        ph = Bvh; pl = Bvl; }
        else               { s = wo[c*512 + ((k&63)<<3) + (k>>6)]; ph = Boh; pl = Bol; }
    }
    ushort hi = f2bf(s);
    ph[o] = hi;
    pl[o] = f2bf(s - bf2f(hi));
}

// ---------------------------------------------------------------------------
// QKV GEMM, split-precision (3 MFMA products). 64x128 tiles.
// q/k: fused RoPE (pairs in adjacent lanes) + coalesced row-major [pos][512].
// v: LDS-transposed epilogue -> coalesced vT[b*512+e][n] stores.
// ---------------------------------------------------------------------------
#define LPITCH 80
__global__ __launch_bounds__(256) void k_gemm_qkv(
    const ushort* __restrict__ xhp, const ushort* __restrict__ xlp,
    const ushort* __restrict__ Bqh, const ushort* __restrict__ Bql,
    const ushort* __restrict__ Bkh, const ushort* __restrict__ Bkl,
    const ushort* __restrict__ Bvh, const ushort* __restrict__ Bvl,
    const float* __restrict__ ang,
    ushort* __restrict__ qa, ushort* __restrict__ ka, ushort* __restrict__ vT)
{
    __shared__ char smem[30720];
    char* xsh = smem;            // 64*LPITCH = 5120
    char* xsl = smem + 5120;     // 5120
    char* wsh = smem + 10240;    // 128*LPITCH = 10240
    char* wsl = smem + 20480;    // 10240
    const int tid = threadIdx.x;
    const int w = tid>>6, l = tid&63, g = l>>4, lr = l&15;
    const int mid = blockIdx.x / 288;
    const int rmb = blockIdx.x - mid*288;
    const int rowblk = rmb >> 2, colblk = rmb & 3;
    const int row0 = rowblk*64, col0 = colblk*128;
    const ushort* Bh; const ushort* Bl;
    if (mid==0)      { Bh = Bqh; Bl = Bql; }
    else if (mid==1) { Bh = Bkh; Bl = Bkl; }
    else             { Bh = Bvh; Bl = Bvl; }

    f32x4 acc[4][2];
#pragma unroll
    for (int mt=0;mt<4;++mt)
#pragma unroll
        for (int nt=0;nt<2;++nt) acc[mt][nt] = (f32x4){0.f,0.f,0.f,0.f};

#pragma unroll 1
    for (int kc = 0; kc < 16; ++kc) {
        const int k0 = kc*32;
        __syncthreads();
#pragma unroll
        for (int u = 0; u < 2; ++u) {            // stage A (hi, lo)
            int i2 = tid + 256*u;
            int tile = i2 >> 8, t2 = i2 & 255;
            int sr = t2 >> 2, sg = t2 & 3;
            const ushort* src = (tile ? xlp : xhp) + (size_t)(row0+sr)*512 + k0 + sg*8;
            char* dst = (tile ? xsl : xsh) + sr*LPITCH + sg*16;
            *reinterpret_cast<uint4*>(dst) = *reinterpret_cast<const uint4*>(src);
        }
#pragma unroll
        for (int u = 0; u < 4; ++u) {            // stage B (hi, lo)
            int i2 = tid + 256*u;
            int tile = i2 >> 9, t2 = i2 & 511;
            int c = t2 >> 2, sg = t2 & 3;
            const ushort* src = (tile ? Bl : Bh) + (size_t)(col0+c)*512 + k0 + sg*8;
            char* dst = (tile ? wsl : wsh) + c*LPITCH + sg*16;
            *reinterpret_cast<uint4*>(dst) = *reinterpret_cast<const uint4*>(src);
        }
        __syncthreads();
        short8v ah[4], al[4], bh_[2], bl_[2];
#pragma unroll
        for (int mt = 0; mt < 4; ++mt) {
            ah[mt] = *reinterpret_cast<const short8v*>(xsh + (mt*16+lr)*LPITCH + g*16);
            al[mt] = *reinterpret_cast<const short8v*>(xsl + (mt*16+lr)*LPITCH + g*16);
        }
#pragma unroll
        for (int nt = 0; nt < 2; ++nt) {
            bh_[nt] = *reinterpret_cast<const short8v*>(wsh + (w*32+nt*16+lr)*LPITCH + g*16);
            bl_[nt] = *reinterpret_cast<const short8v*>(wsl + (w*32+nt*16+lr)*LPITCH + g*16);
        }
#pragma unroll
        for (int mt = 0; mt < 4; ++mt)
#pragma unroll
            for (int nt = 0; nt < 2; ++nt) {
                acc[mt][nt] = __builtin_amdgcn_mfma_f32_16x16x32_bf16(ah[mt], bh_[nt], acc[mt][nt], 0, 0, 0);
                acc[mt][nt] = __builtin_amdgcn_mfma_f32_16x16x32_bf16(ah[mt], bl_[nt], acc[mt][nt], 0, 0, 0);
                acc[mt][nt] = __builtin_amdgcn_mfma_f32_16x16x32_bf16(al[mt], bh_[nt], acc[mt][nt], 0, 0, 0);
            }
    }

    const int b = row0 / NSEQ;
    const int rem0 = row0 - b*NSEQ;
    if (mid < 2) {
        // fused RoPE: pair (v even, v odd) = lanes (lr even, lr odd)
        ushort* dst = (mid==0) ? qa : ka;
        const int odd = lr & 1;
#pragma unroll
        for (int nt = 0; nt < 2; ++nt) {
            int c = col0 + w*32 + nt*16 + lr;     // e = h*64+v
            int pc = (c & 63) >> 1;
            float a_i = ang[pc], a_j = ang[32 + pc];
#pragma unroll
            for (int mt = 0; mt < 4; ++mt)
#pragma unroll
                for (int r = 0; r < 4; ++r) {
                    int rowrem = rem0 + mt*16 + 4*g + r;
                    int i = rowrem / WW, j = rowrem - (rowrem/WW)*WW;
                    float th = (float)i*a_i + (float)j*a_j;
                    float sn, cn; __sincosf(th, &sn, &cn);
                    float own = acc[mt][nt][r];
                    float oth = __shfl_xor(own, 1);
                    float rot = odd ? (oth*sn + own*cn) : (own*cn - oth*sn);
                    dst[(size_t)(b*NSEQ + rowrem)*DD + c] = f2bf(rot);
                }
        }
    } else {
        // v: transpose through LDS, then coalesced vT stores
        __syncthreads();                          // LDS no longer needed by K-loop
        ushort (*tile)[72] = reinterpret_cast<ushort(*)[72]>(smem);   // 128x72 = 18432B
#pragma unroll
        for (int nt = 0; nt < 2; ++nt) {
            int cl = w*32 + nt*16 + lr;
#pragma unroll
            for (int mt = 0; mt < 4; ++mt)
#pragma unroll
                for (int r = 0; r < 4; ++r)
                    tile[cl][mt*16 + 4*g + r] = f2bf(acc[mt][nt][r]);
        }
        __syncthreads();
        int col = tid >> 1, half = tid & 1;
        ushort* dst = vT + ((size_t)(b*DD + col0 + col))*NSEQ + rem0 + half*32;
#pragma unroll
        for (int q2 = 0; q2 < 4; ++q2) {
            uint4 val = *reinterpret_cast<const uint4*>(&tile[col][half*32 + q2*8]);
            *reinterpret_cast<uint4*>(dst + q2*8) = val;
        }
    }
}

// ---------------------------------------------------------------------------
// Output projection GEMM with FUSED split-KV combine in the A-staging:
// A[pos][e] = (Op0*2^{m0-M} + Op1*2^{m1-M}) / (l0*2^{m0-M}+l1*2^{m1-M}).
// B = Bo split (2 products). fp32 out. 64x128 tiles, grid 288.
// ---------------------------------------------------------------------------
__global__ __launch_bounds__(256) void k_gemm_o(
    const ushort* __restrict__ Op, const float2* __restrict__ mlp,
    const ushort* __restrict__ Boh, const ushort* __restrict__ Bol,
    float* __restrict__ out)
{
    __shared__ char xs[64*LPITCH];
    __shared__ char wsh[128*LPITCH], wsl[128*LPITCH];
    const int tid = threadIdx.x;
    const int w = tid>>6, l = tid&63, g = l>>4, lr = l&15;
    const int row0 = (blockIdx.x >> 2)*64;
    const int col0 = (blockIdx.x & 3)*128;
    const int b = row0 / NSEQ;
    const int rem0 = row0 - b*NSEQ;

    f32x4 acc[4][2];
#pragma unroll
    for (int mt=0;mt<4;++mt)
#pragma unroll
        for (int nt=0;nt<2;++nt) acc[mt][nt] = (f32x4){0.f,0.f,0.f,0.f};

#pragma unroll 1
    for (int kc = 0; kc < 16; ++kc) {
        const int k0 = kc*32;
        __syncthreads();
        {   // stage A tile with fused combine: e-chunk [k0,k0+32) lies in head h
            int sr = tid >> 2, sg = tid & 3;
            int h = kc >> 1;
            int vv = (kc & 1)*32 + sg*8;
            size_t arow = (size_t)(b*NHH + h)*NSEQ + rem0 + sr;
            float2 a0 = mlp[arow], a1 = mlp[NROWS + arow];
            float M = fmaxf(a0.x, a1.x);
            float w0 = fexp2(a0.x - M), w1 = fexp2(a1.x - M);
            float inv = 1.f / (a0.y*w0 + a1.y*w1);
            w0 *= inv; w1 *= inv;
            uint4 u0 = *reinterpret_cast<const uint4*>(Op + arow*64 + vv);
            uint4 u1 = *reinterpret_cast<const uint4*>(Op + ((size_t)NROWS + arow)*64 + vv);
            const ushort* s0 = reinterpret_cast<const ushort*>(&u0);
            const ushort* s1 = reinterpret_cast<const ushort*>(&u1);
            ushort res[8];
#pragma unroll
            for (int i2 = 0; i2 < 8; ++i2)
                res[i2] = f2bf(bf2f(s0[i2])*w0 + bf2f(s1[i2])*w1);
            *reinterpret_cast<uint4*>(xs + sr*LPITCH + sg*16) =
                *reinterpret_cast<const uint4*>(res);
        }
#pragma unroll
        for (int u = 0; u < 4; ++u) {   // stage B tiles (hi, lo)
            int i2 = tid + 256*u;
            int tile = i2 >> 9, t2 = i2 & 511;
            int c = t2 >> 2, sg = t2 & 3;
            const ushort* src = (tile ? Bol : Boh) + (size_t)(col0+c)*512 + k0 + sg*8;
            char* dst = (tile ? wsl : wsh) + c*LPITCH + sg*16;
            *reinterpret_cast<uint4*>(dst) = *reinterpret_cast<const uint4*>(src);
        }
        __syncthreads();
        short8v a[4], bh_[2], bl_[2];
#pragma unroll
        for (int mt = 0; mt < 4; ++mt)
            a[mt] = *reinterpret_cast<const short8v*>(xs + (mt*16+lr)*LPITCH + g*16);
#pragma unroll
        for (int nt = 0; nt < 2; ++nt) {
            bh_[nt] = *reinterpret_cast<const short8v*>(wsh + (w*32+nt*16+lr)*LPITCH + g*16);
            bl_[nt] = *reinterpret_cast<const short8v*>(wsl + (w*32+nt*16+lr)*LPITCH + g*16);
        }
#pragma unroll
        for (int mt = 0; mt < 4; ++mt)
#pragma unroll
            for (int nt = 0; nt < 2; ++nt) {
                acc[mt][nt] = __builtin_amdgcn_mfma_f32_16x16x32_bf16(a[mt], bh_[nt], acc[mt][nt], 0, 0, 0);
                acc[mt][nt] = __builtin_amdgcn_mfma_f32_16x16x32_bf16(a[mt], bl_[nt], acc[mt][nt], 0, 0, 0);
            }
    }

#pragma unroll
    for (int mt=0;mt<4;++mt)
#pragma unroll
        for (int r=0;r<4;++r) {
            float* rowp = out + (size_t)(row0 + mt*16 + 4*g + r)*DD + col0 + w*32;
#pragma unroll
            for (int nt=0;nt<2;++nt)
                rowp[nt*16 + lr] = acc[mt][nt][r];
        }
}

// ---------------------------------------------------------------------------
// Flash attention, bf16 MFMA, split-KV (2 splits of 18 chunks).
// q/k row-major [pos][512] (head offset h*64); vT[b*512+e][n].
// Swapped QK^T: lane owns one q-row, in-lane softmax (exp2 domain).
// ---------------------------------------------------------------------------
#define CK 64
#define KP 72              // LDS pitch (bf16 elems) -> 144 B rows
__global__ __launch_bounds__(256) void k_attn_mfma(
    const ushort* __restrict__ qb, const ushort* __restrict__ kb,
    const ushort* __restrict__ vb, ushort* __restrict__ Op,
    float2* __restrict__ mlp)
{
    __shared__ ushort ksm[CK][KP];
    __shared__ ushort vsm[CK][KP];
    __shared__ ushort psm[4][16][KP];    // per-wave P [q][kv]
    const int tid = threadIdx.x;
    const int w = tid >> 6, l = tid & 63;
    const int g = l >> 4, lr = l & 15;
    const int sp  = blockIdx.x / 576;
    const int rest = blockIdx.x - sp*576;
    const int bh = rest / 36;
    const int qc = rest - bh*36;
    const int row0 = qc * 64;
    const int b_ = bh >> 3, h_ = bh & 7;
    const ushort* kbase = kb + (size_t)b_*NSEQ*DD + h_*64;
    const ushort* vbase = vb + ((size_t)(b_*DD + h_*64))*NSEQ;

    // Q fragment (B-operand of swapped QK): col=lr -> q row, k=8g+j -> d
    const ushort* qptr = qb + ((size_t)(b_*NSEQ) + row0 + 16*w + lr)*DD + h_*64 + g*8;
    const short8v qB0 = *reinterpret_cast<const short8v*>(qptr);
    const short8v qB1 = *reinterpret_cast<const short8v*>(qptr + 32);

    float m_ln = -INFINITY, l_ln = 0.f;   // per-lane state for q = lr (log2 domain)
    f32x4 o[4];
#pragma unroll
    for (int vt = 0; vt < 4; ++vt) o[vt] = (f32x4){0.f,0.f,0.f,0.f};

    for (int t = sp*18; t < sp*18 + 18; ++t) {
        __syncthreads();
#pragma unroll
        for (int i = 0; i < 2; ++i) {
            int tau = tid + 256*i;
            int row = tau >> 3, cg = tau & 7;
            *reinterpret_cast<uint4*>(&ksm[row][cg*8]) =
                *reinterpret_cast<const uint4*>(kbase + ((size_t)(t*CK + row))*DD + cg*8);
            *reinterpret_cast<uint4*>(&vsm[row][cg*8]) =
                *reinterpret_cast<const uint4*>(vbase + (size_t)row*NSEQ + t*CK + cg*8);
        }
        __syncthreads();

        // ---- S^T = K Q^T : sc[tile][r] = S[kv=16t+4g+r][q=lr] (log2 units)
        f32x4 sc[4];
#pragma unroll
        for (int tile = 0; tile < 4; ++tile) {
            short8v k0 = *reinterpret_cast<const short8v*>(&ksm[tile*16 + lr][g*8]);
            short8v k1 = *reinterpret_cast<const short8v*>(&ksm[tile*16 + lr][32 + g*8]);
            f32x4 a2 = (f32x4){0.f,0.f,0.f,0.f};
            a2 = __builtin_amdgcn_mfma_f32_16x16x32_bf16(k0, qB0, a2, 0, 0, 0);
            a2 = __builtin_amdgcn_mfma_f32_16x16x32_bf16(k1, qB1, a2, 0, 0, 0);
            sc[tile] = a2;
        }

        // ---- online softmax (exp2): in-lane over 16 values, then reduce over g
        float cm = sc[0][0];
#pragma unroll
        for (int tile = 0; tile < 4; ++tile)
#pragma unroll
            for (int r = 0; r < 4; ++r)
                cm = fmaxf(cm, sc[tile][r]);
        cm = fmaxf(cm, __shfl_xor(cm, 16));
        cm = fmaxf(cm, __shfl_xor(cm, 32));
        float mn = fmaxf(m_ln, cm);
        float f = fexp2(m_ln - mn);
        m_ln = mn;
        float rs = 0.f;
#pragma unroll
        for (int tile = 0; tile < 4; ++tile)
#pragma unroll
            for (int r = 0; r < 4; ++r) {
                float p = fexp2(sc[tile][r] - mn);
                sc[tile][r] = p;
                rs += p;
            }
        rs += __shfl_xor(rs, 16);
        rs += __shfl_xor(rs, 32);
        l_ln = l_ln*f + rs;

        // ---- P pack: 4 consecutive kv per tile -> b64 writes psm[q=lr][16t+4g]
#pragma unroll
        for (int tile = 0; tile < 4; ++tile) {
            uint2 pk;
            pk.x = pack2bf(sc[tile][0], sc[tile][1]);
            pk.y = pack2bf(sc[tile][2], sc[tile][3]);
            *reinterpret_cast<uint2*>(&psm[w][lr][16*tile + 4*g]) = pk;
        }

        // ---- O rescale: row 4g+r needs f of q=4g+r (lane lr'=4g+r in group)
        float f4[4];
#pragma unroll
        for (int r = 0; r < 4; ++r)
            f4[r] = __shfl(f, 4*g + r, 16);
#pragma unroll
        for (int vt = 0; vt < 4; ++vt)
#pragma unroll
            for (int r = 0; r < 4; ++r)
                o[vt][r] *= f4[r];

        // ---- O += P V
#pragma unroll
        for (int half = 0; half < 2; ++half) {
            short8v pA = *reinterpret_cast<const short8v*>(&psm[w][lr][32*half + g*8]);
#pragma unroll
            for (int vt = 0; vt < 4; ++vt) {
                short8v vf = *reinterpret_cast<const short8v*>(&vsm[vt*16 + lr][32*half + g*8]);
                o[vt] = __builtin_amdgcn_mfma_f32_16x16x32_bf16(pA, vf, o[vt], 0, 0, 0);
            }
        }
    }

    // ---- store unnormalized partial O (bf16) + (m,l) per row
    ushort* obase = Op + ((size_t)sp*NROWS + (size_t)bh*NSEQ + row0 + 16*w)*64;
#pragma unroll
    for (int vt = 0; vt < 4; ++vt)
#pragma unroll
        for (int r = 0; r < 4; ++r)
            obase[(4*g + r)*64 + vt*16 + lr] = f2bf(o[vt][r]);
    if (g == 0)
        mlp[sp*NROWS + bh*NSEQ + row0 + 16*w + lr] = make_float2(m_ln, l_ln);
}

// ---------------------------------------------------------------------------
extern "C" void kernel_launch(void* const* d_in, const int* in_sizes, int n_in,
                              void* d_out, int out_size, void* d_ws, size_t ws_size,
                              hipStream_t stream) {
    const float* x   = (const float*)d_in[0];
    const float* wq  = (const float*)d_in[1];
    const float* wk  = (const float*)d_in[2];
    const float* wv  = (const float*)d_in[3];
    const float* wo  = (const float*)d_in[4];
    const float* ang = (const float*)d_in[5];
    float* out = (float*)d_out;

    ushort* xh  = (ushort*)d_ws;         // [4608][512]; aliased as Op[0..1] after qkv
    ushort* xl  = xh + NXE;
    ushort* Bqh = xl + NXE;              // 8 x [512][512]
    ushort* Bql = Bqh + WSZ;
    ushort* Bkh = Bql + WSZ;
    ushort* Bkl = Bkh + WSZ;
    ushort* Bvh = Bkl + WSZ;
    ushort* Bvl = Bvh + WSZ;
    ushort* Boh = Bvl + WSZ;
    ushort* Bol = Boh + WSZ;
    ushort* qa  = Bol + WSZ;             // [4608][512] row-major (e = h*64+v)
    ushort* ka  = qa + NXE;
    ushort* vT  = ka + NXE;              // [b*512+e][2304]
    ushort* Op  = xh;                    // [2][36864][64] partial O (aliases x splits)
    float2* mlp = (float2*)Bqh;          // [2][36864] (aliases dead Bq panels)

    k_prep<<<(NXE + 4*WSZ)/256, 256, 0, stream>>>(x, wq, wk, wv, wo,
        xh, xl, Bqh, Bql, Bkh, Bkl, Bvh, Bvl, Boh, Bol);
    k_gemm_qkv<<<864, 256, 0, stream>>>(xh, xl, Bqh, Bql, Bkh, Bkl, Bvh, Bvl,
        ang, qa, ka, vT);
    k_attn_mfma<<<1152, 256, 0, stream>>>(qa, ka, vT, Op, mlp);
    k_gemm_o<<<288, 256, 0, stream>>>(Op, mlp, Boh, Bol, out);
}